// Round 6
// baseline (1955.357 us; speedup 1.0000x reference)
//
#include <hip/hip_runtime.h>

// PatchVQVAETransformer forward, round 6:
//  - patch encoder decomposed into 5 big-grid kernels (pk1..pk5), bit-exact
//    arithmetic vs patch2 (same loop orders/expressions) -> z bit-identical.
//    Intermediates alias bufA/bufC/tb (dead during patch phase).
//  - VQ f32 GEMM BK 16->32 (same k order -> S bit-identical).
//  - MFMA attention, bf16 MFMA GEMMs, exact VQ finish: unchanged from r5.

#define SQRT1_2F 0.70710678118654752440f

typedef __attribute__((ext_vector_type(8))) short short8;
typedef __attribute__((ext_vector_type(4))) float f32x4;
typedef __attribute__((ext_vector_type(8))) unsigned short ushort8;
typedef unsigned short ushort;

__device__ __forceinline__ float gelu_exact(float v) {
  return 0.5f * v * (1.0f + erff(v * SQRT1_2F));
}

__device__ __forceinline__ ushort f2b_rne(float f) {
  unsigned u = __float_as_uint(f);
  unsigned r = (u + 0x7fffu + ((u >> 16) & 1u)) >> 16;
  return (ushort)r;
}

__device__ __forceinline__ float b2f(ushort u) {
  return __uint_as_float(((unsigned)u) << 16);
}

__device__ __forceinline__ void gload16(const void* g, void* l) {
  __builtin_amdgcn_global_load_lds(
      (const __attribute__((address_space(1))) void*)g,
      (__attribute__((address_space(3))) void*)l, 16, 0, 0);
}

// ---------------------------------------------------------------------------
// One-time setup: q16 = lq@wq^T + bq, wkvT, woutT. 1 block, 64 threads.
// ---------------------------------------------------------------------------
__global__ __launch_bounds__(64) void patch_setup_kernel(
    const float* __restrict__ lq, const float* __restrict__ win,
    const float* __restrict__ bin, const float* __restrict__ wout,
    float* __restrict__ q16, float* __restrict__ wkvT,
    float* __restrict__ woutT) {
  const int tid = threadIdx.x;
#pragma unroll
  for (int q = 0; q < 8; q++) {
    int e = tid + (q << 6);
    int i = e >> 5, c = e & 31;
    const float* wr = win + (size_t)c * 32;
    float acc = bin[c];
#pragma unroll
    for (int d = 0; d < 32; d++) acc += lq[(i << 5) + d] * wr[d];
    q16[e] = acc;
  }
#pragma unroll
  for (int q = 0; q < 32; q++) {
    int e = tid + (q << 6);
    int w = e >> 10, d = (e >> 5) & 31, c = e & 31;
    wkvT[e] = win[(size_t)(32 + (w << 5) + c) * 32 + d];
  }
#pragma unroll
  for (int q = 0; q < 16; q++) {
    int e = tid + (q << 6);
    int d = e >> 5, c = e & 31;
    woutT[e] = wout[(size_t)c * 32 + d];
  }
}

// ---------------------------------------------------------------------------
// LN over 16 rows x 32 cols at row-stride 34 in LDS, in place. 4 lanes/row.
// (identical code to r4/r5 -> bitwise-identical results)
// ---------------------------------------------------------------------------
__device__ __forceinline__ void ln_16xS(float* buf, const float* g,
                                        const float* bb, int tid) {
  int row = tid >> 2, sub = tid & 3;
  int c0 = sub << 3;
  float* r = buf + row * 34 + c0;
  float v[8];
  float s = 0.f, s2 = 0.f;
#pragma unroll
  for (int n = 0; n < 8; n++) {
    float t = r[n];
    v[n] = t; s += t; s2 += t * t;
  }
  s += __shfl_xor(s, 1);  s += __shfl_xor(s, 2);
  s2 += __shfl_xor(s2, 1); s2 += __shfl_xor(s2, 2);
  float m = s * (1.0f / 32.0f);
  float var = s2 * (1.0f / 32.0f) - m * m;
  float inv = 1.0f / sqrtf(var + 1e-5f);
#pragma unroll
  for (int n = 0; n < 8; n++)
    r[n] = (v[n] - m) * inv * g[c0 + n] + bb[c0 + n];
}

// ---------------------------------------------------------------------------
// pk1: kv in-proj. out kvb[p][w][j][c] (16384x1024). One thread per output.
// Block = 256 thr covers (p, q2): w = q2>>1, 8 j rows. Bit-exact phase 1+2.
// ---------------------------------------------------------------------------
__global__ __launch_bounds__(256) void pk1_inproj(
    const float* __restrict__ x, const float* __restrict__ pos,
    const float* __restrict__ wkvT, const float* __restrict__ bin,
    float* __restrict__ kvb) {
  __shared__ float sxp[256];   // (xp+pos) rows jbase..jbase+7
  const int b = blockIdx.x, t = threadIdx.x;
  const int p = b >> 2, q2 = b & 3;
  const int w = q2 >> 1, jbase = (q2 & 1) << 3;
  sxp[t] = x[(size_t)p * 512 + (jbase << 5) + t] + pos[(jbase << 5) + t];
  __syncthreads();
  const int jl = t >> 5, c = t & 31;
  const float* wt = wkvT + (w << 10) + c;
  float acc = bin[32 + (w << 5) + c];
#pragma unroll
  for (int d = 0; d < 32; d++) acc += sxp[(jl << 5) + d] * wt[d << 5];
  kvb[(size_t)b * 256 + t] = acc;
}

// ---------------------------------------------------------------------------
// pk2: scores + softmax + A@V. One thread per (p,h,i); block = 4 patches.
// Bit-exact phases 3b/4/5. Writes so[p][i][c] for c in head h's 8 columns.
// ---------------------------------------------------------------------------
__global__ __launch_bounds__(256) void pk2_attn(
    const float* __restrict__ kvb, const float* __restrict__ q16,
    float* __restrict__ so) {
  __shared__ float skv[4096];    // 4 patches x [2][16][32]
  __shared__ float sq16[16 * 33];
  const int b = blockIdx.x, t = threadIdx.x;
#pragma unroll
  for (int q = 0; q < 16; q++)
    skv[t + (q << 8)] = kvb[(size_t)b * 4096 + t + (q << 8)];
  if (t < 128) {
#pragma unroll
    for (int q = 0; q < 4; q++) {
      int e = t + (q << 7);
      sq16[(e >> 5) * 33 + (e & 31)] = q16[e];
    }
  }
  __syncthreads();
  const int pl = t >> 6, hh = (t >> 4) & 3, i = t & 15;
  const int p = (b << 2) + pl;
  const float* kp = skv + (pl << 10);
  const int hd = hh << 3;

  float sc[16];
#pragma unroll
  for (int j = 0; j < 16; j++) {
    float acc = 0.f;
#pragma unroll
    for (int d = 0; d < 8; d++)
      acc += sq16[i * 33 + hd + d] * kp[(j << 5) + hd + d];
    sc[j] = acc * 0.35355339059327373f;
  }
  // softmax (identical op sequence to patch2 phase 4)
  {
    float mx = sc[0];
#pragma unroll
    for (int j = 1; j < 16; j++) mx = fmaxf(mx, sc[j]);
    float sm = 0.f;
    float ev[16];
#pragma unroll
    for (int j = 0; j < 16; j++) { ev[j] = expf(sc[j] - mx); sm += ev[j]; }
    float inv = 1.0f / sm;
#pragma unroll
    for (int j = 0; j < 16; j++) sc[j] = ev[j] * inv;
  }
  // o = A @ v for the 8 columns of head hh
  float* orow = so + (size_t)p * 512 + (i << 5) + hd;
#pragma unroll
  for (int c8 = 0; c8 < 8; c8++) {
    const int c = hd + c8;
    float acc = 0.f;
#pragma unroll
    for (int j = 0; j < 16; j++) acc += sc[j] * kp[512 + (j << 5) + c];
    orow[c8] = acc;
  }
}

// ---------------------------------------------------------------------------
// pk3: out-proj + lq residual + LN1. One 64-thr block per patch.
// Bit-exact phases 6/7. Writes st (=xn) to global.
// ---------------------------------------------------------------------------
__global__ __launch_bounds__(64) void pk3_outproj(
    const float* __restrict__ so_g, const float* __restrict__ woutT,
    const float* __restrict__ bout, const float* __restrict__ lq,
    const float* __restrict__ ln1g, const float* __restrict__ ln1b,
    float* __restrict__ st_g) {
  __shared__ float sso[544], sst[544];
  const int p = blockIdx.x, t = threadIdx.x;
#pragma unroll
  for (int q = 0; q < 8; q++) {
    int e = t + (q << 6);
    sso[(e >> 5) * 34 + (e & 31)] = so_g[(size_t)p * 512 + e];
  }
  __syncthreads();
#pragma unroll
  for (int q = 0; q < 8; q++) {
    int e = t + (q << 6);
    int i = e >> 5, c = e & 31;
    const float* wt = woutT + c;
    float acc = bout[c];
#pragma unroll
    for (int d = 0; d < 32; d++) acc += sso[i * 34 + d] * wt[d << 5];
    sst[i * 34 + c] = acc + lq[(i << 5) + c];
  }
  __syncthreads();
  ln_16xS(sst, ln1g, ln1b, t);
  __syncthreads();
#pragma unroll
  for (int q = 0; q < 8; q++) {
    int e = t + (q << 6);
    st_g[(size_t)p * 512 + e] = sst[(e >> 5) * 34 + (e & 31)];
  }
}

// ---------------------------------------------------------------------------
// pk4: FFN1. One thread per (p,i,u) output (16384x16x64). Bit-exact phase 8.
// ---------------------------------------------------------------------------
__global__ __launch_bounds__(256) void pk4_ffn1(
    const float* __restrict__ st_g, const float* __restrict__ w1,
    const float* __restrict__ b1, float* __restrict__ sh_g) {
  __shared__ float sst4[128];   // 4 rows of st
  const int b = blockIdx.x, t = threadIdx.x;
  const int p = b >> 2, ib = (b & 3) << 2;
  if (t < 128) sst4[t] = st_g[(size_t)p * 512 + (ib << 5) + t];
  __syncthreads();
  const int il = t >> 6, u = t & 63;
  float acc = b1[u];
#pragma unroll
  for (int d = 0; d < 32; d++) acc += sst4[(il << 5) + d] * w1[(d << 6) + u];
  sh_g[(size_t)b * 256 + t] = gelu_exact(acc);
}

// ---------------------------------------------------------------------------
// pk5: FFN2 + residual + LN2 + z = xp + xo. One 64-thr block per patch.
// Bit-exact phases 9/10/11.
// ---------------------------------------------------------------------------
__global__ __launch_bounds__(64) void pk5_ffn2(
    const float* __restrict__ sh_g, const float* __restrict__ st_g,
    const float* __restrict__ x, const float* __restrict__ w2,
    const float* __restrict__ b2, const float* __restrict__ ln2g,
    const float* __restrict__ ln2b, float* __restrict__ z) {
  __shared__ float ssh[16 * 66], sst[544], sso[544];
  const int p = blockIdx.x, t = threadIdx.x;
#pragma unroll
  for (int q = 0; q < 16; q++) {
    int e = t + (q << 6);
    ssh[(e >> 6) * 66 + (e & 63)] = sh_g[(size_t)p * 1024 + e];
  }
#pragma unroll
  for (int q = 0; q < 8; q++) {
    int e = t + (q << 6);
    sst[(e >> 5) * 34 + (e & 31)] = st_g[(size_t)p * 512 + e];
  }
  __syncthreads();
#pragma unroll
  for (int q = 0; q < 8; q++) {
    int e = t + (q << 6);
    int i = e >> 5, c = e & 31;
    float acc = b2[c];
#pragma unroll
    for (int u = 0; u < 64; u++) acc += ssh[i * 66 + u] * w2[(u << 5) + c];
    sso[i * 34 + c] = acc + sst[i * 34 + c];
  }
  __syncthreads();
  ln_16xS(sso, ln2g, ln2b, t);
  __syncthreads();
  const float* xp = x + (size_t)p * 512;
#pragma unroll
  for (int q = 0; q < 8; q++) {
    int e = t + (q << 6);
    z[(size_t)p * 512 + e] = xp[e] + sso[(e >> 5) * 34 + (e & 31)];
  }
}

// ---------------------------------------------------------------------------
__global__ __launch_bounds__(64) void cbnorm_kernel(const float* __restrict__ cb,
                                                    float* __restrict__ cbn) {
  int c = blockIdx.x, lane = threadIdx.x;
  const float* r = cb + (size_t)c * 512 + lane * 8;
  float4 a = *(const float4*)r, b = *(const float4*)(r + 4);
  float s = a.x*a.x + a.y*a.y + a.z*a.z + a.w*a.w +
            b.x*b.x + b.y*b.y + b.z*b.z + b.w*b.w;
#pragma unroll
  for (int off = 1; off < 64; off <<= 1) s += __shfl_xor(s, off);
  if (lane == 0) cbn[c] = s;
}

// ---------------------------------------------------------------------------
// f32 GEMM (VQ scores): C = A @ B^T. 128x128 tile, BK=32 (same ascending-k
// order as BK=16 version -> S bit-identical).
// ---------------------------------------------------------------------------
__global__ __launch_bounds__(256) void gemm_f32_bt(
    const float* __restrict__ A, const float* __restrict__ B,
    float* __restrict__ C, int M, int N, int K) {
  __shared__ float As[32][132];
  __shared__ float Bs[32][132];
  const int nbx = N >> 7;
  const int bx = blockIdx.x % nbx, by = blockIdx.x / nbx;
  const int tid = threadIdx.x;
  const int ty = tid >> 4, tx = tid & 15;
  const int m0 = by << 7, n0 = bx << 7;
  float acc[8][8] = {};

  for (int k0 = 0; k0 < K; k0 += 32) {
#pragma unroll
    for (int q = 0; q < 4; q++) {
      int e = tid + (q << 8);
      int row = e >> 3, kq = e & 7;
      const float4 v = *(const float4*)(A + (size_t)(m0 + row) * K + k0 + (kq << 2));
      As[kq * 4 + 0][row] = v.x; As[kq * 4 + 1][row] = v.y;
      As[kq * 4 + 2][row] = v.z; As[kq * 4 + 3][row] = v.w;
    }
#pragma unroll
    for (int q = 0; q < 4; q++) {
      int e = tid + (q << 8);
      int row = e >> 3, kq = e & 7;
      const float4 v = *(const float4*)(B + (size_t)(n0 + row) * K + k0 + (kq << 2));
      Bs[kq * 4 + 0][row] = v.x; Bs[kq * 4 + 1][row] = v.y;
      Bs[kq * 4 + 2][row] = v.z; Bs[kq * 4 + 3][row] = v.w;
    }
    __syncthreads();
#pragma unroll
    for (int k = 0; k < 32; k++) {
      float a[8], b[8];
      *(float4*)(a)     = *(const float4*)&As[k][ty * 8];
      *(float4*)(a + 4) = *(const float4*)&As[k][ty * 8 + 4];
      *(float4*)(b)     = *(const float4*)&Bs[k][tx * 8];
      *(float4*)(b + 4) = *(const float4*)&Bs[k][tx * 8 + 4];
#pragma unroll
      for (int i = 0; i < 8; i++)
#pragma unroll
        for (int j = 0; j < 8; j++) acc[i][j] = fmaf(a[i], b[j], acc[i][j]);
    }
    __syncthreads();
  }

#pragma unroll
  for (int i = 0; i < 8; i++) {
    float* Cr = C + (size_t)(m0 + ty * 8 + i) * N + n0 + tx * 8;
    *(float4*)(Cr)     = *(float4*)(&acc[i][0]);
    *(float4*)(Cr + 4) = *(float4*)(&acc[i][4]);
  }
}

// ---------------------------------------------------------------------------
// bf16 MFMA GEMM (unchanged from r3-r5).
// ---------------------------------------------------------------------------
template <int OUTMODE>
__global__ __launch_bounds__(256) void gemm_bf16_kernel(
    const ushort* __restrict__ A, const ushort* __restrict__ B,
    const float* __restrict__ bias, void* __restrict__ Cout,
    int M, int N, int K) {
  __shared__ ushort As[4096];
  __shared__ ushort Bs[4096];
  const int nbx = N >> 7;
  const int bx = blockIdx.x % nbx, by = blockIdx.x / nbx;
  const int m0 = by << 7, n0 = bx << 7;
  const int tid = threadIdx.x;
  const int wid = tid >> 6, lane = tid & 63;
  const int wr = wid >> 1, wc = wid & 1;
  const int l15 = lane & 15, lk = lane >> 4;

  const f32x4 fzero = {0.f, 0.f, 0.f, 0.f};
  f32x4 acc[4][4];
#pragma unroll
  for (int i = 0; i < 4; i++)
#pragma unroll
    for (int j = 0; j < 4; j++) acc[i][j] = fzero;

  for (int k0 = 0; k0 < K; k0 += 32) {
#pragma unroll
    for (int c = 0; c < 2; c++) {
      const int I = tid + (c << 8);
      const int r = I >> 2, kk = (I & 3) << 3;
      gload16(A + (size_t)(m0 + r) * K + k0 + kk,
              As + (size_t)((wid << 6) + (c << 8)) * 8);
      gload16(B + (size_t)(n0 + r) * K + k0 + kk,
              Bs + (size_t)((wid << 6) + (c << 8)) * 8);
    }
    __syncthreads();

    short8 a[4], b[4];
#pragma unroll
    for (int m = 0; m < 4; m++) {
      const int ar = (wr << 6) + (m << 4) + l15;
      a[m] = *(const short8*)(As + ar * 32 + lk * 8);
      const int br = (wc << 6) + (m << 4) + l15;
      b[m] = *(const short8*)(Bs + br * 32 + lk * 8);
    }
#pragma unroll
    for (int m = 0; m < 4; m++)
#pragma unroll
      for (int n = 0; n < 4; n++)
        acc[m][n] = __builtin_amdgcn_mfma_f32_16x16x32_bf16(a[m], b[n],
                                                            acc[m][n], 0, 0, 0);
    __syncthreads();
  }

  float bv[4];
#pragma unroll
  for (int n = 0; n < 4; n++)
    bv[n] = bias[n0 + (wc << 6) + (n << 4) + l15];

#pragma unroll
  for (int m = 0; m < 4; m++) {
#pragma unroll
    for (int n = 0; n < 4; n++) {
      const int gcol = n0 + (wc << 6) + (n << 4) + l15;
#pragma unroll
      for (int r = 0; r < 4; r++) {
        const int grow = m0 + (wr << 6) + (m << 4) + (lk << 2) + r;
        float v = acc[m][n][r] + bv[n];
        if (OUTMODE == 0) {
          ((float*)Cout)[(size_t)grow * N + gcol] = v;
        } else if (OUTMODE == 1) {
          ((ushort*)Cout)[(size_t)grow * N + gcol] = f2b_rne(gelu_exact(v));
        } else {
          ((ushort*)Cout)[(size_t)grow * N + gcol] = f2b_rne(v);
        }
      }
    }
  }
}

// ---------------------------------------------------------------------------
// Weight conversions.
// ---------------------------------------------------------------------------
__global__ void cvt_flat(const float* __restrict__ in, ushort* __restrict__ out,
                         int n) {
  int i = blockIdx.x * blockDim.x + threadIdx.x;
  const int stride = gridDim.x * blockDim.x;
  for (; i < n; i += stride) out[i] = f2b_rne(in[i]);
}

__global__ __launch_bounds__(256) void cvt_tr(const float* __restrict__ in,
                                              ushort* __restrict__ out,
                                              int R, int C) {
  __shared__ float tile[32][33];
  const int bc = blockIdx.x, br = blockIdx.y, lay = blockIdx.z;
  const float* src = in + (size_t)lay * R * C;
  ushort* dst = out + (size_t)lay * R * C;
  const int tid = threadIdx.x;
#pragma unroll
  for (int q = 0; q < 4; q++) {
    int idx = tid + (q << 8);
    int rr = idx >> 5, cc = idx & 31;
    tile[rr][cc] = src[(size_t)(br * 32 + rr) * C + bc * 32 + cc];
  }
  __syncthreads();
#pragma unroll
  for (int q = 0; q < 4; q++) {
    int idx = tid + (q << 8);
    int co = idx >> 5, ro = idx & 31;
    dst[(size_t)(bc * 32 + co) * R + br * 32 + ro] = f2b_rne(tile[ro][co]);
  }
}

// ---------------------------------------------------------------------------
// VQ finish (f32, exact numpy-replicating argmin).
// ---------------------------------------------------------------------------
__global__ __launch_bounds__(64) void vq_finish_kernel(
    const float* __restrict__ S, const float* __restrict__ cb,
    const float* __restrict__ cbn, const float* __restrict__ z,
    const float* __restrict__ tf_pos, float* __restrict__ t,
    ushort* __restrict__ th,
    float* __restrict__ idx_out, float* __restrict__ loss_out) {
  const int r = blockIdx.x, lane = threadIdx.x;
  const float* zr = z + (size_t)r * 512;

  float s2 = 0.f;
  {
    const float* zp = zr + lane * 8;
    float4 a = *(const float4*)zp, b = *(const float4*)(zp + 4);
    s2 = a.x*a.x + a.y*a.y + a.z*a.z + a.w*a.w +
         b.x*b.x + b.y*b.y + b.z*b.z + b.w*b.w;
  }
#pragma unroll
  for (int off = 1; off < 64; off <<= 1) s2 += __shfl_xor(s2, off);

  const float* Sr = S + (size_t)r * 1024;
  float best = __int_as_float(0x7f7fffff);
  int bi = 0x7fffffff;
  for (int c = lane; c < 1024; c += 64) {
    float d = (s2 + cbn[c]) - 2.0f * Sr[c];
    if (d < best) { best = d; bi = c; }
  }
#pragma unroll
  for (int off = 1; off < 64; off <<= 1) {
    float ob = __shfl_xor(best, off);
    int oi = __shfl_xor(bi, off);
    if (ob < best || (ob == best && oi < bi)) { best = ob; bi = oi; }
  }

  const float* q = cb + (size_t)bi * 512;
  const float* pr = tf_pos + (size_t)(r & 255) * 512;
  float lsum = 0.f;
  float tv[8];
#pragma unroll
  for (int n = 0; n < 8; n++) {
    int c = lane * 8 + n;
    float qv = q[c];
    float diff = qv - zr[c];
    lsum += diff * diff;
    tv[n] = qv + pr[c];
    t[(size_t)r * 512 + c] = tv[n];
  }
  {
    ushort8 w;
#pragma unroll
    for (int n = 0; n < 8; n++) w[n] = f2b_rne(tv[n]);
    *(ushort8*)(th + (size_t)r * 512 + lane * 8) = w;
  }
#pragma unroll
  for (int off = 1; off < 64; off <<= 1) lsum += __shfl_xor(lsum, off);
  if (lane == 0) {
    atomicAdd(loss_out, lsum * (1.25f / 8388608.0f));
    idx_out[r] = (float)bi;
  }
}

// ---------------------------------------------------------------------------
// MFMA flash attention (unchanged from r5).
// ---------------------------------------------------------------------------
__global__ __launch_bounds__(64) void attn_mfma_kernel(
    const ushort* __restrict__ qkv, ushort* __restrict__ o) {
  __shared__ ushort lds[8192];
  char* KsB = (char*)lds;
  char* VtB = (char*)(lds + 4096);
  const int bid = blockIdx.x;
  const int xcd = bid & 7, slot = bid >> 3;
  const int b = (xcd << 3) | (slot >> 5);
  const int h = (slot >> 2) & 7;
  const int qb = slot & 3;
  const int lane = threadIdx.x;
  const int l15 = lane & 15, lk4 = lane >> 4;

  short8 qf[4][2];
#pragma unroll
  for (int m = 0; m < 4; m++)
#pragma unroll
    for (int kc = 0; kc < 2; kc++)
      qf[m][kc] = *(const short8*)(qkv +
          (size_t)(b * 256 + qb * 64 + m * 16 + l15) * 1536 +
          h * 64 + kc * 32 + lk4 * 8);

  const f32x4 fz = {0.f, 0.f, 0.f, 0.f};
  f32x4 O[4][4];
#pragma unroll
  for (int m = 0; m < 4; m++)
#pragma unroll
    for (int n = 0; n < 4; n++) O[m][n] = fz;
  float lsum[4][4];
#pragma unroll
  for (int m = 0; m < 4; m++)
#pragma unroll
    for (int r = 0; r < 4; r++) lsum[m][r] = 0.f;

  for (int jt = 0; jt <= qb; jt++) {
    ushort8 kv[8], vv[8];
    const ushort* krow = qkv + (size_t)(b * 256 + jt * 64 + lane) * 1536 +
                         512 + h * 64;
#pragma unroll
    for (int u = 0; u < 8; u++) kv[u] = ((const ushort8*)krow)[u];
#pragma unroll
    for (int u = 0; u < 8; u++) vv[u] = ((const ushort8*)(krow + 512))[u];
    __syncthreads();
    {
      const int rx = (lane & 7) << 4;
#pragma unroll
      for (int u = 0; u < 8; u++)
        *(ushort8*)(KsB + lane * 128 + ((u << 4) ^ rx)) = kv[u];
#pragma unroll
      for (int u = 0; u < 8; u++)
#pragma unroll
        for (int i = 0; i < 8; i++) {
          const int d = u * 8 + i;
          *(ushort*)(VtB + ((d * 128 + lane * 2) ^ ((d & 7) << 4))) =
              (ushort)vv[u][i];
        }
    }
    __syncthreads();

    f32x4 sacc[4][4];
#pragma unroll
    for (int m = 0; m < 4; m++)
#pragma unroll
      for (int n = 0; n < 4; n++) sacc[m][n] = fz;
#pragma unroll
    for (int kc = 0; kc < 2; kc++) {
      short8 bf[4];
#pragma unroll
      for (int n = 0; n < 4; n++) {
        const int row = n * 16 + l15;
        bf[n] = *(const short8*)(KsB + row * 128 +
                                 ((kc * 64 + lk4 * 16) ^ ((row & 7) << 4)));
      }
#pragma unroll
      for (int m = 0; m < 4; m++)
#pragma unroll
        for (int n = 0; n < 4; n++)
          sacc[m][n] = __builtin_amdgcn_mfma_f32_16x16x32_bf16(
              qf[m][kc], bf[n], sacc[m][n], 0, 0, 0);
    }
    __syncthreads();

    const bool diag = (jt == qb);
#pragma unroll
    for (int m = 0; m < 4; m++)
#pragma unroll
      for (int n = 0; n < 4; n++)
#pragma unroll
        for (int r = 0; r < 4; r++) {
          const int ql = m * 16 + lk4 * 4 + r;
          const int jl = n * 16 + l15;
          float e = __expf(sacc[m][n][r] * 0.125f);
          if (diag && jl > ql) e = 0.f;
          const ushort pu = f2b_rne(e);
          lsum[m][r] += b2f(pu);
          *(ushort*)(KsB + ql * 128 + ((jl * 2) ^ ((ql & 7) << 4))) = pu;
        }
    __syncthreads();

#pragma unroll
    for (int kc = 0; kc < 2; kc++) {
      short8 pf[4], vf[4];
#pragma unroll
      for (int m = 0; m < 4; m++) {
        const int row = m * 16 + l15;
        pf[m] = *(const short8*)(KsB + row * 128 +
                                 ((kc * 64 + lk4 * 16) ^ ((row & 7) << 4)));
      }
#pragma unroll
      for (int n = 0; n < 4; n++) {
        const int row = n * 16 + l15;
        vf[n] = *(const short8*)(VtB + row * 128 +
                                 ((kc * 64 + lk4 * 16) ^ ((row & 7) << 4)));
      }
#pragma unroll
      for (int m = 0; m < 4; m++)
#pragma unroll
        for (int n = 0; n < 4; n++)
          O[m][n] = __builtin_amdgcn_mfma_f32_16x16x32_bf16(
              pf[m], vf[n], O[m][n], 0, 0, 0);
    }
  }

  float inv[4][4];
#pragma unroll
  for (int m = 0; m < 4; m++)
#pragma unroll
    for (int r = 0; r < 4; r++) {
      float v = lsum[m][r];
      v += __shfl_xor(v, 1); v += __shfl_xor(v, 2);
      v += __shfl_xor(v, 4); v += __shfl_xor(v, 8);
      inv[m][r] = 1.0f / v;
    }
#pragma unroll
  for (int m = 0; m < 4; m++)
#pragma unroll
    for (int n = 0; n < 4; n++)
#pragma unroll
      for (int r = 0; r < 4; r++) {
        const int row = b * 256 + qb * 64 + m * 16 + lk4 * 4 + r;
        const int col = h * 64 + n * 16 + l15;
        o[(size_t)row * 512 + col] = f2b_rne(O[m][n][r] * inv[m][r]);
      }
}

// ---------------------------------------------------------------------------
// LayerNorm over 512 (+residual). Writes f32 out and optional bf16 copy.
// ---------------------------------------------------------------------------
__global__ __launch_bounds__(256) void ln_kernel(
    const float* __restrict__ xin, const float* __restrict__ addin,
    const float* __restrict__ g, const float* __restrict__ bb,
    float* __restrict__ outp, ushort* __restrict__ outb) {
  const int r = blockIdx.x * 4 + (threadIdx.x >> 6);
  const int lane = threadIdx.x & 63;
  const float* xr = xin + (size_t)r * 512 + lane * 8;
  float v[8];
  *(float4*)(v)     = *(const float4*)(xr);
  *(float4*)(v + 4) = *(const float4*)(xr + 4);
  if (addin) {
    const float* ar = addin + (size_t)r * 512 + lane * 8;
    float w[8];
    *(float4*)(w)     = *(const float4*)(ar);
    *(float4*)(w + 4) = *(const float4*)(ar + 4);
#pragma unroll
    for (int n = 0; n < 8; n++) v[n] += w[n];
  }
  float s = 0.f, s2 = 0.f;
#pragma unroll
  for (int n = 0; n < 8; n++) { s += v[n]; s2 += v[n] * v[n]; }
#pragma unroll
  for (int off = 1; off < 64; off <<= 1) {
    s += __shfl_xor(s, off);
    s2 += __shfl_xor(s2, off);
  }
  float m = s * (1.0f / 512.0f);
  float var = s2 * (1.0f / 512.0f) - m * m;
  float inv = 1.0f / sqrtf(var + 1e-5f);
  const int c0 = lane * 8;
  float outv[8];
#pragma unroll
  for (int n = 0; n < 8; n++) outv[n] = (v[n] - m) * inv * g[c0 + n] + bb[c0 + n];
  float* orow = outp + (size_t)r * 512 + c0;
  *(float4*)(orow)     = *(float4*)(outv);
  *(float4*)(orow + 4) = *(float4*)(outv + 4);
  if (outb) {
    ushort8 w;
#pragma unroll
    for (int n = 0; n < 8; n++) w[n] = f2b_rne(outv[n]);
    *(ushort8*)(outb + (size_t)r * 512 + c0) = w;
  }
}

// ---------------------------------------------------------------------------
extern "C" void kernel_launch(void* const* d_in, const int* in_sizes, int n_in,
                              void* d_out, int out_size, void* d_ws, size_t ws_size,
                              hipStream_t stream) {
  const float* x       = (const float*)d_in[0];
  const float* pa_lq   = (const float*)d_in[1];
  const float* pa_pos  = (const float*)d_in[2];
  const float* pa_win  = (const float*)d_in[3];
  const float* pa_bin  = (const float*)d_in[4];
  const float* pa_wout = (const float*)d_in[5];
  const float* pa_bout = (const float*)d_in[6];
  const float* pa_ln1g = (const float*)d_in[7];
  const float* pa_ln1b = (const float*)d_in[8];
  const float* pa_ln2g = (const float*)d_in[9];
  const float* pa_ln2b = (const float*)d_in[10];
  const float* pa_w1   = (const float*)d_in[11];
  const float* pa_b1   = (const float*)d_in[12];
  const float* pa_w2   = (const float*)d_in[13];
  const float* pa_b2   = (const float*)d_in[14];
  const float* cb      = (const float*)d_in[15];
  const float* tf_pos  = (const float*)d_in[16];
  const float* tf_win  = (const float*)d_in[17];
  const float* tf_bin  = (const float*)d_in[18];
  const float* tf_wout = (const float*)d_in[19];
  const float* tf_bout = (const float*)d_in[20];
  const float* tf_ln1g = (const float*)d_in[21];
  const float* tf_ln1b = (const float*)d_in[22];
  const float* tf_ln2g = (const float*)d_in[23];
  const float* tf_ln2b = (const float*)d_in[24];
  const float* tf_w1   = (const float*)d_in[25];
  const float* tf_b1   = (const float*)d_in[26];
  const float* tf_w2   = (const float*)d_in[27];
  const float* tf_b2   = (const float*)d_in[28];
  const float* fin_g   = (const float*)d_in[29];
  const float* fin_b   = (const float*)d_in[30];

  float* yout = (float*)d_out;            // 16384 x 512
  float* loss_out = yout + 8388608;       // scalar
  float* idx_out = loss_out + 1;          // 16384 (as float)

  float* ws   = (float*)d_ws;
  float* z    = ws;                   // 8388608
  float* tb   = z + 8388608;          // 8388608  (patch: st ; later residual)
  float* bufA = tb + 8388608;         // 16777216 (patch: kvb, sh ; later S/qkv)
  float* bufC = bufA + 16777216;      // 8388608  (patch: so ; later proj out)
  float* wreg = bufC + 8388608;       // 6291456
  float* treg = wreg + 6291456;       // 4194304
  float* cbn  = treg + 4194304;       // 1024
  float* q16  = cbn + 1024;           // 512
  float* wkvT = q16 + 512;            // 2048
  float* woutT = wkvT + 2048;         // 1024

  ushort* win_b  = (ushort*)wreg;
  ushort* wout_b = win_b + 3145728;
  ushort* w1t_b  = wout_b + 1048576;
  ushort* w2t_b  = w1t_b + 4194304;
  ushort* tbh    = (ushort*)treg;
  ushort* qkvh   = (ushort*)bufA;
  ushort* abh    = (ushort*)z;

  hipMemsetAsync(loss_out, 0, sizeof(float), stream);
  cbnorm_kernel<<<1024, 64, 0, stream>>>(cb, cbn);
  patch_setup_kernel<<<1, 64, 0, stream>>>(pa_lq, pa_win, pa_bin, pa_wout,
                                           q16, wkvT, woutT);

  // patch encoder pipeline (bit-exact vs r4/r5 patch2)
  pk1_inproj<<<65536, 256, 0, stream>>>(x, pa_pos, wkvT, pa_bin, bufA);
  pk2_attn<<<4096, 256, 0, stream>>>(bufA, q16, bufC);
  pk3_outproj<<<16384, 64, 0, stream>>>(bufC, woutT, pa_bout, pa_lq,
                                        pa_ln1g, pa_ln1b, tb);
  pk4_ffn1<<<65536, 256, 0, stream>>>(tb, pa_w1, pa_b1, bufA);
  pk5_ffn2<<<16384, 64, 0, stream>>>(bufA, tb, x, pa_w2, pa_b2,
                                     pa_ln2g, pa_ln2b, z);

  cvt_flat<<<2048, 256, 0, stream>>>(tf_win, win_b, 3145728);
  cvt_flat<<<1024, 256, 0, stream>>>(tf_wout, wout_b, 1048576);
  cvt_tr<<<dim3(64, 16, 4), 256, 0, stream>>>(tf_w1, w1t_b, 512, 2048);
  cvt_tr<<<dim3(16, 64, 4), 256, 0, stream>>>(tf_w2, w2t_b, 2048, 512);

  gemm_f32_bt<<<dim3(128 * 8), 256, 0, stream>>>(z, cb, bufA, 16384, 1024, 512);
  vq_finish_kernel<<<16384, 64, 0, stream>>>(bufA, cb, cbn, z, tf_pos, tb, tbh,
                                             idx_out, loss_out);

  for (int l = 0; l < 4; l++) {
    gemm_bf16_kernel<2><<<dim3(128 * 12), 256, 0, stream>>>(
        tbh, win_b + (size_t)l * 1536 * 512, tf_bin + l * 1536, qkvh,
        16384, 1536, 512);
    attn_mfma_kernel<<<dim3(2048), 64, 0, stream>>>(qkvh, abh);
    gemm_bf16_kernel<0><<<dim3(128 * 4), 256, 0, stream>>>(
        abh, wout_b + (size_t)l * 512 * 512, tf_bout + l * 512, bufC,
        16384, 512, 512);
    ln_kernel<<<dim3(4096), 256, 0, stream>>>(tb, bufC, tf_ln1g + l * 512,
                                              tf_ln1b + l * 512, tb, tbh);
    gemm_bf16_kernel<1><<<dim3(128 * 16), 256, 0, stream>>>(
        tbh, w1t_b + (size_t)l * 1048576, tf_b1 + l * 2048, qkvh,
        16384, 2048, 512);
    gemm_bf16_kernel<0><<<dim3(128 * 4), 256, 0, stream>>>(
        qkvh, w2t_b + (size_t)l * 1048576, tf_b2 + l * 512, bufC,
        16384, 512, 2048);
    ln_kernel<<<dim3(4096), 256, 0, stream>>>(tb, bufC, tf_ln2g + l * 512,
                                              tf_ln2b + l * 512, tb, tbh);
  }
  ln_kernel<<<dim3(4096), 256, 0, stream>>>(tb, nullptr, fin_g, fin_b, yout,
                                            nullptr);

  (void)in_sizes; (void)n_in; (void)out_size; (void)ws_size;
}

// Round 7
// 1938.090 us; speedup vs baseline: 1.0089x; 1.0089x over previous
//
#include <hip/hip_runtime.h>

// PatchVQVAETransformer forward, round 7:
//  - f32 VQ GEMM: B-fragment remapped to two 4-col groups (tx*4, 64+tx*4) ->
//    LDS read conflicts 4-way -> 2-way(free). Same per-output k order ->
//    S bit-identical -> idx exact.
//  - patch encoder re-merged to 2 kernels (pkA: inproj+attn, pkB: rest),
//    expressions verbatim from r6 -> z bit-identical, ~350MB less traffic.
//  - bf16 MFMA GEMMs, MFMA attention, VQ finish: unchanged.

#define SQRT1_2F 0.70710678118654752440f

typedef __attribute__((ext_vector_type(8))) short short8;
typedef __attribute__((ext_vector_type(4))) float f32x4;
typedef __attribute__((ext_vector_type(8))) unsigned short ushort8;
typedef unsigned short ushort;

__device__ __forceinline__ float gelu_exact(float v) {
  return 0.5f * v * (1.0f + erff(v * SQRT1_2F));
}

__device__ __forceinline__ ushort f2b_rne(float f) {
  unsigned u = __float_as_uint(f);
  unsigned r = (u + 0x7fffu + ((u >> 16) & 1u)) >> 16;
  return (ushort)r;
}

__device__ __forceinline__ float b2f(ushort u) {
  return __uint_as_float(((unsigned)u) << 16);
}

__device__ __forceinline__ void gload16(const void* g, void* l) {
  __builtin_amdgcn_global_load_lds(
      (const __attribute__((address_space(1))) void*)g,
      (__attribute__((address_space(3))) void*)l, 16, 0, 0);
}

// ---------------------------------------------------------------------------
// One-time setup: q16 = lq@wq^T + bq, wkvT, woutT. 1 block, 64 threads.
// ---------------------------------------------------------------------------
__global__ __launch_bounds__(64) void patch_setup_kernel(
    const float* __restrict__ lq, const float* __restrict__ win,
    const float* __restrict__ bin, const float* __restrict__ wout,
    float* __restrict__ q16, float* __restrict__ wkvT,
    float* __restrict__ woutT) {
  const int tid = threadIdx.x;
#pragma unroll
  for (int q = 0; q < 8; q++) {
    int e = tid + (q << 6);
    int i = e >> 5, c = e & 31;
    const float* wr = win + (size_t)c * 32;
    float acc = bin[c];
#pragma unroll
    for (int d = 0; d < 32; d++) acc += lq[(i << 5) + d] * wr[d];
    q16[e] = acc;
  }
#pragma unroll
  for (int q = 0; q < 32; q++) {
    int e = tid + (q << 6);
    int w = e >> 10, d = (e >> 5) & 31, c = e & 31;
    wkvT[e] = win[(size_t)(32 + (w << 5) + c) * 32 + d];
  }
#pragma unroll
  for (int q = 0; q < 16; q++) {
    int e = tid + (q << 6);
    int d = e >> 5, c = e & 31;
    woutT[e] = wout[(size_t)c * 32 + d];
  }
}

// ---------------------------------------------------------------------------
// LN over 16 rows x 32 cols at row-stride 34 in LDS, in place. 4 lanes/row.
// ---------------------------------------------------------------------------
__device__ __forceinline__ void ln_16xS(float* buf, const float* g,
                                        const float* bb, int tid) {
  int row = tid >> 2, sub = tid & 3;
  int c0 = sub << 3;
  float* r = buf + row * 34 + c0;
  float v[8];
  float s = 0.f, s2 = 0.f;
#pragma unroll
  for (int n = 0; n < 8; n++) {
    float t = r[n];
    v[n] = t; s += t; s2 += t * t;
  }
  s += __shfl_xor(s, 1);  s += __shfl_xor(s, 2);
  s2 += __shfl_xor(s2, 1); s2 += __shfl_xor(s2, 2);
  float m = s * (1.0f / 32.0f);
  float var = s2 * (1.0f / 32.0f) - m * m;
  float inv = 1.0f / sqrtf(var + 1e-5f);
#pragma unroll
  for (int n = 0; n < 8; n++)
    r[n] = (v[n] - m) * inv * g[c0 + n] + bb[c0 + n];
}

// ---------------------------------------------------------------------------
// pkA: in-proj + scores/softmax/AV for 4 patches per 256-thr block.
// Expressions verbatim from r6 pk1/pk2 -> bit-exact. Writes so (16384x512).
// ---------------------------------------------------------------------------
__global__ __launch_bounds__(256) void pkA_kernel(
    const float* __restrict__ x, const float* __restrict__ pos,
    const float* __restrict__ wkvT, const float* __restrict__ bin,
    const float* __restrict__ q16, float* __restrict__ so) {
  __shared__ float sxp[2048];    // [4][16][32] = xp+pos
  __shared__ float skv[4096];    // [4][2][16][32]
  __shared__ float sq16[16 * 33];
  const int blk = blockIdx.x, t = threadIdx.x;
  const int p0 = blk << 2;

#pragma unroll
  for (int q = 0; q < 8; q++) {
    int e = t + (q << 8);
    int pl = e >> 9, r = e & 511;
    sxp[e] = x[(size_t)(p0 + pl) * 512 + r] + pos[r];
  }
  if (t < 128) {
#pragma unroll
    for (int q = 0; q < 4; q++) {
      int e = t + (q << 7);
      sq16[(e >> 5) * 33 + (e & 31)] = q16[e];
    }
  }
  __syncthreads();

  // kv in-proj: 4096 outputs / 256 thr = 16 each
#pragma unroll
  for (int q = 0; q < 16; q++) {
    int e = t + (q << 8);
    int pl = e >> 10, rr = e & 1023;
    int w = rr >> 9, rj = rr & 511, j = rj >> 5, c = rj & 31;
    const float* wt = wkvT + (w << 10) + c;
    const float* sx = sxp + (pl << 9) + (j << 5);
    float acc = bin[32 + (w << 5) + c];
#pragma unroll
    for (int d = 0; d < 32; d++) acc += sx[d] * wt[d << 5];
    skv[e] = acc;
  }
  __syncthreads();

  // attention: one thread per (patch, head, row)
  const int pl = t >> 6, hh = (t >> 4) & 3, i = t & 15;
  const int p = p0 + pl;
  const float* kp = skv + (pl << 10);
  const int hd = hh << 3;

  float sc[16];
#pragma unroll
  for (int j = 0; j < 16; j++) {
    float acc = 0.f;
#pragma unroll
    for (int d = 0; d < 8; d++)
      acc += sq16[i * 33 + hd + d] * kp[(j << 5) + hd + d];
    sc[j] = acc * 0.35355339059327373f;
  }
  {
    float mx = sc[0];
#pragma unroll
    for (int j = 1; j < 16; j++) mx = fmaxf(mx, sc[j]);
    float sm = 0.f;
    float ev[16];
#pragma unroll
    for (int j = 0; j < 16; j++) { ev[j] = expf(sc[j] - mx); sm += ev[j]; }
    float inv = 1.0f / sm;
#pragma unroll
    for (int j = 0; j < 16; j++) sc[j] = ev[j] * inv;
  }
  float* orow = so + (size_t)p * 512 + (i << 5) + hd;
#pragma unroll
  for (int c8 = 0; c8 < 8; c8++) {
    const int c = hd + c8;
    float acc = 0.f;
#pragma unroll
    for (int j = 0; j < 16; j++) acc += sc[j] * kp[512 + (j << 5) + c];
    orow[c8] = acc;
  }
}

// ---------------------------------------------------------------------------
// pkB: out-proj+LN1+FFN1+FFN2+LN2+z per patch (64 thr). Verbatim patch2
// phases 6-11 -> bit-exact z.
// ---------------------------------------------------------------------------
__global__ __launch_bounds__(64) void pkB_kernel(
    const float* __restrict__ so_g, const float* __restrict__ x,
    const float* __restrict__ woutT, const float* __restrict__ bout,
    const float* __restrict__ lq,
    const float* __restrict__ ln1g, const float* __restrict__ ln1b,
    const float* __restrict__ w1, const float* __restrict__ b1,
    const float* __restrict__ w2, const float* __restrict__ b2,
    const float* __restrict__ ln2g, const float* __restrict__ ln2b,
    float* __restrict__ z) {
  __shared__ float sso[544], sst[544], ssh[1056];
  const int p = blockIdx.x, t = threadIdx.x;
#pragma unroll
  for (int q = 0; q < 8; q++) {
    int e = t + (q << 6);
    sso[(e >> 5) * 34 + (e & 31)] = so_g[(size_t)p * 512 + e];
  }
  __syncthreads();
#pragma unroll
  for (int q = 0; q < 8; q++) {
    int e = t + (q << 6);
    int i = e >> 5, c = e & 31;
    const float* wt = woutT + c;
    float acc = bout[c];
#pragma unroll
    for (int d = 0; d < 32; d++) acc += sso[i * 34 + d] * wt[d << 5];
    sst[i * 34 + c] = acc + lq[(i << 5) + c];
  }
  __syncthreads();
  ln_16xS(sst, ln1g, ln1b, t);
  __syncthreads();
#pragma unroll
  for (int q = 0; q < 16; q++) {
    int i = q, u = t;
    float acc = b1[u];
#pragma unroll
    for (int d = 0; d < 32; d++) acc += sst[i * 34 + d] * w1[(d << 6) + u];
    ssh[i * 66 + u] = gelu_exact(acc);
  }
  __syncthreads();
#pragma unroll
  for (int q = 0; q < 8; q++) {
    int e = t + (q << 6);
    int i = e >> 5, c = e & 31;
    float acc = b2[c];
#pragma unroll
    for (int u = 0; u < 64; u++) acc += ssh[i * 66 + u] * w2[(u << 5) + c];
    sso[i * 34 + c] = acc + sst[i * 34 + c];
  }
  __syncthreads();
  ln_16xS(sso, ln2g, ln2b, t);
  __syncthreads();
  const float* xp = x + (size_t)p * 512;
#pragma unroll
  for (int q = 0; q < 8; q++) {
    int e = t + (q << 6);
    z[(size_t)p * 512 + e] = xp[e] + sso[(e >> 5) * 34 + (e & 31)];
  }
}

// ---------------------------------------------------------------------------
__global__ __launch_bounds__(64) void cbnorm_kernel(const float* __restrict__ cb,
                                                    float* __restrict__ cbn) {
  int c = blockIdx.x, lane = threadIdx.x;
  const float* r = cb + (size_t)c * 512 + lane * 8;
  float4 a = *(const float4*)r, b = *(const float4*)(r + 4);
  float s = a.x*a.x + a.y*a.y + a.z*a.z + a.w*a.w +
            b.x*b.x + b.y*b.y + b.z*b.z + b.w*b.w;
#pragma unroll
  for (int off = 1; off < 64; off <<= 1) s += __shfl_xor(s, off);
  if (lane == 0) cbn[c] = s;
}

// ---------------------------------------------------------------------------
// f32 GEMM (VQ scores): C = A @ B^T. 128x128 tile, BK=32.
// B-fragment cols = {tx*4..+3, 64+tx*4..+3} -> Bs reads 2-way (free).
// Per-output ascending-k order unchanged -> S bit-identical.
// ---------------------------------------------------------------------------
__global__ __launch_bounds__(256) void gemm_f32_bt(
    const float* __restrict__ A, const float* __restrict__ B,
    float* __restrict__ C, int M, int N, int K) {
  __shared__ float As[32][132];
  __shared__ float Bs[32][132];
  const int nbx = N >> 7;
  const int bx = blockIdx.x % nbx, by = blockIdx.x / nbx;
  const int tid = threadIdx.x;
  const int ty = tid >> 4, tx = tid & 15;
  const int m0 = by << 7, n0 = bx << 7;
  float acc[8][8] = {};

  for (int k0 = 0; k0 < K; k0 += 32) {
#pragma unroll
    for (int q = 0; q < 4; q++) {
      int e = tid + (q << 8);
      int row = e >> 3, kq = e & 7;
      const float4 v = *(const float4*)(A + (size_t)(m0 + row) * K + k0 + (kq << 2));
      As[kq * 4 + 0][row] = v.x; As[kq * 4 + 1][row] = v.y;
      As[kq * 4 + 2][row] = v.z; As[kq * 4 + 3][row] = v.w;
    }
#pragma unroll
    for (int q = 0; q < 4; q++) {
      int e = tid + (q << 8);
      int row = e >> 3, kq = e & 7;
      const float4 v = *(const float4*)(B + (size_t)(n0 + row) * K + k0 + (kq << 2));
      Bs[kq * 4 + 0][row] = v.x; Bs[kq * 4 + 1][row] = v.y;
      Bs[kq * 4 + 2][row] = v.z; Bs[kq * 4 + 3][row] = v.w;
    }
    __syncthreads();
#pragma unroll
    for (int k = 0; k < 32; k++) {
      float a[8], b[8];
      *(float4*)(a)     = *(const float4*)&As[k][ty * 8];
      *(float4*)(a + 4) = *(const float4*)&As[k][ty * 8 + 4];
      *(float4*)(b)     = *(const float4*)&Bs[k][tx * 4];
      *(float4*)(b + 4) = *(const float4*)&Bs[k][64 + tx * 4];
#pragma unroll
      for (int i = 0; i < 8; i++)
#pragma unroll
        for (int j = 0; j < 8; j++) acc[i][j] = fmaf(a[i], b[j], acc[i][j]);
    }
    __syncthreads();
  }

#pragma unroll
  for (int i = 0; i < 8; i++) {
    float* Cr = C + (size_t)(m0 + ty * 8 + i) * N + n0;
    *(float4*)(Cr + tx * 4)      = *(float4*)(&acc[i][0]);
    *(float4*)(Cr + 64 + tx * 4) = *(float4*)(&acc[i][4]);
  }
}

// ---------------------------------------------------------------------------
// bf16 MFMA GEMM (unchanged from r3-r6).
// ---------------------------------------------------------------------------
template <int OUTMODE>
__global__ __launch_bounds__(256) void gemm_bf16_kernel(
    const ushort* __restrict__ A, const ushort* __restrict__ B,
    const float* __restrict__ bias, void* __restrict__ Cout,
    int M, int N, int K) {
  __shared__ ushort As[4096];
  __shared__ ushort Bs[4096];
  const int nbx = N >> 7;
  const int bx = blockIdx.x % nbx, by = blockIdx.x / nbx;
  const int m0 = by << 7, n0 = bx << 7;
  const int tid = threadIdx.x;
  const int wid = tid >> 6, lane = tid & 63;
  const int wr = wid >> 1, wc = wid & 1;
  const int l15 = lane & 15, lk = lane >> 4;

  const f32x4 fzero = {0.f, 0.f, 0.f, 0.f};
  f32x4 acc[4][4];
#pragma unroll
  for (int i = 0; i < 4; i++)
#pragma unroll
    for (int j = 0; j < 4; j++) acc[i][j] = fzero;

  for (int k0 = 0; k0 < K; k0 += 32) {
#pragma unroll
    for (int c = 0; c < 2; c++) {
      const int I = tid + (c << 8);
      const int r = I >> 2, kk = (I & 3) << 3;
      gload16(A + (size_t)(m0 + r) * K + k0 + kk,
              As + (size_t)((wid << 6) + (c << 8)) * 8);
      gload16(B + (size_t)(n0 + r) * K + k0 + kk,
              Bs + (size_t)((wid << 6) + (c << 8)) * 8);
    }
    __syncthreads();

    short8 a[4], b[4];
#pragma unroll
    for (int m = 0; m < 4; m++) {
      const int ar = (wr << 6) + (m << 4) + l15;
      a[m] = *(const short8*)(As + ar * 32 + lk * 8);
      const int br = (wc << 6) + (m << 4) + l15;
      b[m] = *(const short8*)(Bs + br * 32 + lk * 8);
    }
#pragma unroll
    for (int m = 0; m < 4; m++)
#pragma unroll
      for (int n = 0; n < 4; n++)
        acc[m][n] = __builtin_amdgcn_mfma_f32_16x16x32_bf16(a[m], b[n],
                                                            acc[m][n], 0, 0, 0);
    __syncthreads();
  }

  float bv[4];
#pragma unroll
  for (int n = 0; n < 4; n++)
    bv[n] = bias[n0 + (wc << 6) + (n << 4) + l15];

#pragma unroll
  for (int m = 0; m < 4; m++) {
#pragma unroll
    for (int n = 0; n < 4; n++) {
      const int gcol = n0 + (wc << 6) + (n << 4) + l15;
#pragma unroll
      for (int r = 0; r < 4; r++) {
        const int grow = m0 + (wr << 6) + (m << 4) + (lk << 2) + r;
        float v = acc[m][n][r] + bv[n];
        if (OUTMODE == 0) {
          ((float*)Cout)[(size_t)grow * N + gcol] = v;
        } else if (OUTMODE == 1) {
          ((ushort*)Cout)[(size_t)grow * N + gcol] = f2b_rne(gelu_exact(v));
        } else {
          ((ushort*)Cout)[(size_t)grow * N + gcol] = f2b_rne(v);
        }
      }
    }
  }
}

// ---------------------------------------------------------------------------
// Weight conversions.
// ---------------------------------------------------------------------------
__global__ void cvt_flat(const float* __restrict__ in, ushort* __restrict__ out,
                         int n) {
  int i = blockIdx.x * blockDim.x + threadIdx.x;
  const int stride = gridDim.x * blockDim.x;
  for (; i < n; i += stride) out[i] = f2b_rne(in[i]);
}

__global__ __launch_bounds__(256) void cvt_tr(const float* __restrict__ in,
                                              ushort* __restrict__ out,
                                              int R, int C) {
  __shared__ float tile[32][33];
  const int bc = blockIdx.x, br = blockIdx.y, lay = blockIdx.z;
  const float* src = in + (size_t)lay * R * C;
  ushort* dst = out + (size_t)lay * R * C;
  const int tid = threadIdx.x;
#pragma unroll
  for (int q = 0; q < 4; q++) {
    int idx = tid + (q << 8);
    int rr = idx >> 5, cc = idx & 31;
    tile[rr][cc] = src[(size_t)(br * 32 + rr) * C + bc * 32 + cc];
  }
  __syncthreads();
#pragma unroll
  for (int q = 0; q < 4; q++) {
    int idx = tid + (q << 8);
    int co = idx >> 5, ro = idx & 31;
    dst[(size_t)(bc * 32 + co) * R + br * 32 + ro] = f2b_rne(tile[ro][co]);
  }
}

// ---------------------------------------------------------------------------
// VQ finish (f32, exact numpy-replicating argmin).
// ---------------------------------------------------------------------------
__global__ __launch_bounds__(64) void vq_finish_kernel(
    const float* __restrict__ S, const float* __restrict__ cb,
    const float* __restrict__ cbn, const float* __restrict__ z,
    const float* __restrict__ tf_pos, float* __restrict__ t,
    ushort* __restrict__ th,
    float* __restrict__ idx_out, float* __restrict__ loss_out) {
  const int r = blockIdx.x, lane = threadIdx.x;
  const float* zr = z + (size_t)r * 512;

  float s2 = 0.f;
  {
    const float* zp = zr + lane * 8;
    float4 a = *(const float4*)zp, b = *(const float4*)(zp + 4);
    s2 = a.x*a.x + a.y*a.y + a.z*a.z + a.w*a.w +
         b.x*b.x + b.y*b.y + b.z*b.z + b.w*b.w;
  }
#pragma unroll
  for (int off = 1; off < 64; off <<= 1) s2 += __shfl_xor(s2, off);

  const float* Sr = S + (size_t)r * 1024;
  float best = __int_as_float(0x7f7fffff);
  int bi = 0x7fffffff;
  for (int c = lane; c < 1024; c += 64) {
    float d = (s2 + cbn[c]) - 2.0f * Sr[c];
    if (d < best) { best = d; bi = c; }
  }
#pragma unroll
  for (int off = 1; off < 64; off <<= 1) {
    float ob = __shfl_xor(best, off);
    int oi = __shfl_xor(bi, off);
    if (ob < best || (ob == best && oi < bi)) { best = ob; bi = oi; }
  }

  const float* q = cb + (size_t)bi * 512;
  const float* pr = tf_pos + (size_t)(r & 255) * 512;
  float lsum = 0.f;
  float tv[8];
#pragma unroll
  for (int n = 0; n < 8; n++) {
    int c = lane * 8 + n;
    float qv = q[c];
    float diff = qv - zr[c];
    lsum += diff * diff;
    tv[n] = qv + pr[c];
    t[(size_t)r * 512 + c] = tv[n];
  }
  {
    ushort8 w;
#pragma unroll
    for (int n = 0; n < 8; n++) w[n] = f2b_rne(tv[n]);
    *(ushort8*)(th + (size_t)r * 512 + lane * 8) = w;
  }
#pragma unroll
  for (int off = 1; off < 64; off <<= 1) lsum += __shfl_xor(lsum, off);
  if (lane == 0) {
    atomicAdd(loss_out, lsum * (1.25f / 8388608.0f));
    idx_out[r] = (float)bi;
  }
}

// ---------------------------------------------------------------------------
// MFMA flash attention (unchanged from r5/r6).
// ---------------------------------------------------------------------------
__global__ __launch_bounds__(64) void attn_mfma_kernel(
    const ushort* __restrict__ qkv, ushort* __restrict__ o) {
  __shared__ ushort lds[8192];
  char* KsB = (char*)lds;
  char* VtB = (char*)(lds + 4096);
  const int bid = blockIdx.x;
  const int xcd = bid & 7, slot = bid >> 3;
  const int b = (xcd << 3) | (slot >> 5);
  const int h = (slot >> 2) & 7;
  const int qb = slot & 3;
  const int lane = threadIdx.x;
  const int l15 = lane & 15, lk4 = lane >> 4;

  short8 qf[4][2];
#pragma unroll
  for (int m = 0; m < 4; m++)
#pragma unroll
    for (int kc = 0; kc < 2; kc++)
      qf[m][kc] = *(const short8*)(qkv +
          (size_t)(b * 256 + qb * 64 + m * 16 + l15) * 1536 +
          h * 64 + kc * 32 + lk4 * 8);

  const f32x4 fz = {0.f, 0.f, 0.f, 0.f};
  f32x4 O[4][4];
#pragma unroll
  for (int m = 0; m < 4; m++)
#pragma unroll
    for (int n = 0; n < 4; n++) O[m][n] = fz;
  float lsum[4][4];
#pragma unroll
  for (int m = 0; m < 4; m++)
#pragma unroll
    for (int r = 0; r < 4; r++) lsum[m][r] = 0.f;

  for (int jt = 0; jt <= qb; jt++) {
    ushort8 kv[8], vv[8];
    const ushort* krow = qkv + (size_t)(b * 256 + jt * 64 + lane) * 1536 +
                         512 + h * 64;
#pragma unroll
    for (int u = 0; u < 8; u++) kv[u] = ((const ushort8*)krow)[u];
#pragma unroll
    for (int u = 0; u < 8; u++) vv[u] = ((const ushort8*)(krow + 512))[u];
    __syncthreads();
    {
      const int rx = (lane & 7) << 4;
#pragma unroll
      for (int u = 0; u < 8; u++)
        *(ushort8*)(KsB + lane * 128 + ((u << 4) ^ rx)) = kv[u];
#pragma unroll
      for (int u = 0; u < 8; u++)
#pragma unroll
        for (int i = 0; i < 8; i++) {
          const int d = u * 8 + i;
          *(ushort*)(VtB + ((d * 128 + lane * 2) ^ ((d & 7) << 4))) =
              (ushort)vv[u][i];
        }
    }
    __syncthreads();

    f32x4 sacc[4][4];
#pragma unroll
    for (int m = 0; m < 4; m++)
#pragma unroll
      for (int n = 0; n < 4; n++) sacc[m][n] = fz;
#pragma unroll
    for (int kc = 0; kc < 2; kc++) {
      short8 bf[4];
#pragma unroll
      for (int n = 0; n < 4; n++) {
        const int row = n * 16 + l15;
        bf[n] = *(const short8*)(KsB + row * 128 +
                                 ((kc * 64 + lk4 * 16) ^ ((row & 7) << 4)));
      }
#pragma unroll
      for (int m = 0; m < 4; m++)
#pragma unroll
        for (int n = 0; n < 4; n++)
          sacc[m][n] = __builtin_amdgcn_mfma_f32_16x16x32_bf16(
              qf[m][kc], bf[n], sacc[m][n], 0, 0, 0);
    }
    __syncthreads();

    const bool diag = (jt == qb);
#pragma unroll
    for (int m = 0; m < 4; m++)
#pragma unroll
      for (int n = 0; n < 4; n++)
#pragma unroll
        for (int r = 0; r < 4; r++) {
          const int ql = m * 16 + lk4 * 4 + r;
          const int jl = n * 16 + l15;
          float e = __expf(sacc[m][n][r] * 0.125f);
          if (diag && jl > ql) e = 0.f;
          const ushort pu = f2b_rne(e);
          lsum[m][r] += b2f(pu);
          *(ushort*)(KsB + ql * 128 + ((jl * 2) ^ ((ql & 7) << 4))) = pu;
        }
    __syncthreads();

#pragma unroll
    for (int kc = 0; kc < 2; kc++) {
      short8 pf[4], vf[4];
#pragma unroll
      for (int m = 0; m < 4; m++) {
        const int row = m * 16 + l15;
        pf[m] = *(const short8*)(KsB + row * 128 +
                                 ((kc * 64 + lk4 * 16) ^ ((row & 7) << 4)));
      }
#pragma unroll
      for (int n = 0; n < 4; n++) {
        const int row = n * 16 + l15;
        vf[n] = *(const short8*)(VtB + row * 128 +
                                 ((kc * 64 + lk4 * 16) ^ ((row & 7) << 4)));
      }
#pragma unroll
      for (int m = 0; m < 4; m++)
#pragma unroll
        for (int n = 0; n < 4; n++)
          O[m][n] = __builtin_amdgcn_mfma_f32_16x16x32_bf16(
              pf[m], vf[n], O[m][n], 0, 0, 0);
    }
  }

  float inv[4][4];
#pragma unroll
  for (int m = 0; m < 4; m++)
#pragma unroll
    for (int r = 0; r < 4; r++) {
      float v = lsum[m][r];
      v += __shfl_xor(v, 1); v += __shfl_xor(v, 2);
      v += __shfl_xor(v, 4); v += __shfl_xor(v, 8);
      inv[m][r] = 1.0f / v;
    }
#pragma unroll
  for (int m = 0; m < 4; m++)
#pragma unroll
    for (int n = 0; n < 4; n++)
#pragma unroll
      for (int r = 0; r < 4; r++) {
        const int row = b * 256 + qb * 64 + m * 16 + lk4 * 4 + r;
        const int col = h * 64 + n * 16 + l15;
        o[(size_t)row * 512 + col] = f2b_rne(O[m][n][r] * inv[m][r]);
      }
}

// ---------------------------------------------------------------------------
// LayerNorm over 512 (+residual). Writes f32 out and optional bf16 copy.
// ---------------------------------------------------------------------------
__global__ __launch_bounds__(256) void ln_kernel(
    const float* __restrict__ xin, const float* __restrict__ addin,
    const float* __restrict__ g, const float* __restrict__ bb,
    float* __restrict__ outp, ushort* __restrict__ outb) {
  const int r = blockIdx.x * 4 + (threadIdx.x >> 6);
  const int lane = threadIdx.x & 63;
  const float* xr = xin + (size_t)r * 512 + lane * 8;
  float v[8];
  *(float4*)(v)     = *(const float4*)(xr);
  *(float4*)(v + 4) = *(const float4*)(xr + 4);
  if (addin) {
    const float* ar = addin + (size_t)r * 512 + lane * 8;
    float w[8];
    *(float4*)(w)     = *(const float4*)(ar);
    *(float4*)(w + 4) = *(const float4*)(ar + 4);
#pragma unroll
    for (int n = 0; n < 8; n++) v[n] += w[n];
  }
  float s = 0.f, s2 = 0.f;
#pragma unroll
  for (int n = 0; n < 8; n++) { s += v[n]; s2 += v[n] * v[n]; }
#pragma unroll
  for (int off = 1; off < 64; off <<= 1) {
    s += __shfl_xor(s, off);
    s2 += __shfl_xor(s2, off);
  }
  float m = s * (1.0f / 512.0f);
  float var = s2 * (1.0f / 512.0f) - m * m;
  float inv = 1.0f / sqrtf(var + 1e-5f);
  const int c0 = lane * 8;
  float outv[8];
#pragma unroll
  for (int n = 0; n < 8; n++) outv[n] = (v[n] - m) * inv * g[c0 + n] + bb[c0 + n];
  float* orow = outp + (size_t)r * 512 + c0;
  *(float4*)(orow)     = *(float4*)(outv);
  *(float4*)(orow + 4) = *(float4*)(outv + 4);
  if (outb) {
    ushort8 w;
#pragma unroll
    for (int n = 0; n < 8; n++) w[n] = f2b_rne(outv[n]);
    *(ushort8*)(outb + (size_t)r * 512 + c0) = w;
  }
}

// ---------------------------------------------------------------------------
extern "C" void kernel_launch(void* const* d_in, const int* in_sizes, int n_in,
                              void* d_out, int out_size, void* d_ws, size_t ws_size,
                              hipStream_t stream) {
  const float* x       = (const float*)d_in[0];
  const float* pa_lq   = (const float*)d_in[1];
  const float* pa_pos  = (const float*)d_in[2];
  const float* pa_win  = (const float*)d_in[3];
  const float* pa_bin  = (const float*)d_in[4];
  const float* pa_wout = (const float*)d_in[5];
  const float* pa_bout = (const float*)d_in[6];
  const float* pa_ln1g = (const float*)d_in[7];
  const float* pa_ln1b = (const float*)d_in[8];
  const float* pa_ln2g = (const float*)d_in[9];
  const float* pa_ln2b = (const float*)d_in[10];
  const float* pa_w1   = (const float*)d_in[11];
  const float* pa_b1   = (const float*)d_in[12];
  const float* pa_w2   = (const float*)d_in[13];
  const float* pa_b2   = (const float*)d_in[14];
  const float* cb      = (const float*)d_in[15];
  const float* tf_pos  = (const float*)d_in[16];
  const float* tf_win  = (const float*)d_in[17];
  const float* tf_bin  = (const float*)d_in[18];
  const float* tf_wout = (const float*)d_in[19];
  const float* tf_bout = (const float*)d_in[20];
  const float* tf_ln1g = (const float*)d_in[21];
  const float* tf_ln1b = (const float*)d_in[22];
  const float* tf_ln2g = (const float*)d_in[23];
  const float* tf_ln2b = (const float*)d_in[24];
  const float* tf_w1   = (const float*)d_in[25];
  const float* tf_b1   = (const float*)d_in[26];
  const float* tf_w2   = (const float*)d_in[27];
  const float* tf_b2   = (const float*)d_in[28];
  const float* fin_g   = (const float*)d_in[29];
  const float* fin_b   = (const float*)d_in[30];

  float* yout = (float*)d_out;            // 16384 x 512
  float* loss_out = yout + 8388608;       // scalar
  float* idx_out = loss_out + 1;          // 16384 (as float)

  float* ws   = (float*)d_ws;
  float* z    = ws;                   // 8388608
  float* tb   = z + 8388608;          // 8388608
  float* bufA = tb + 8388608;         // 16777216
  float* bufC = bufA + 16777216;      // 8388608
  float* wreg = bufC + 8388608;       // 6291456
  float* treg = wreg + 6291456;       // 4194304
  float* cbn  = treg + 4194304;       // 1024
  float* q16  = cbn + 1024;           // 512
  float* wkvT = q16 + 512;            // 2048
  float* woutT = wkvT + 2048;         // 1024

  ushort* win_b  = (ushort*)wreg;
  ushort* wout_b = win_b + 3145728;
  ushort* w1t_b  = wout_b + 1048576;
  ushort* w2t_b  = w1t_b + 4194304;
  ushort* tbh    = (ushort*)treg;
  ushort* qkvh   = (ushort*)bufA;
  ushort* abh    = (ushort*)z;

  hipMemsetAsync(loss_out, 0, sizeof(float), stream);
  cbnorm_kernel<<<1024, 64, 0, stream>>>(cb, cbn);
  patch_setup_kernel<<<1, 64, 0, stream>>>(pa_lq, pa_win, pa_bin, pa_wout,
                                           q16, wkvT, woutT);

  // patch encoder (2 kernels, bit-exact vs r6)
  pkA_kernel<<<4096, 256, 0, stream>>>(x, pa_pos, wkvT, pa_bin, q16, bufC);
  pkB_kernel<<<16384, 64, 0, stream>>>(bufC, x, woutT, pa_bout, pa_lq,
                                       pa_ln1g, pa_ln1b, pa_w1, pa_b1,
                                       pa_w2, pa_b2, pa_ln2g, pa_ln2b, z);

  cvt_flat<<<2048, 256, 0, stream>>>(tf_win, win_b, 3145728);
  cvt_flat<<<1024, 256, 0, stream>>>(tf_wout, wout_b, 1048576);
  cvt_tr<<<dim3(64, 16, 4), 256, 0, stream>>>(tf_w1, w1t_b, 512, 2048);
  cvt_tr<<<dim3(16, 64, 4), 256, 0, stream>>>(tf_w2, w2t_b, 2048, 512);

  gemm_f32_bt<<<dim3(128 * 8), 256, 0, stream>>>(z, cb, bufA, 16384, 1024, 512);
  vq_finish_kernel<<<16384, 64, 0, stream>>>(bufA, cb, cbn, z, tf_pos, tb, tbh,
                                             idx_out, loss_out);

  for (int l = 0; l < 4; l++) {
    gemm_bf16_kernel<2><<<dim3(128 * 12), 256, 0, stream>>>(
        tbh, win_b + (size_t)l * 1536 * 512, tf_bin + l * 1536, qkvh,
        16384, 1536, 512);
    attn_mfma_kernel<<<dim3(2048), 64, 0, stream>>>(qkvh, abh);
    gemm_bf16_kernel<0><<<dim3(128 * 4), 256, 0, stream>>>(
        abh, wout_b + (size_t)l * 512 * 512, tf_bout + l * 512, bufC,
        16384, 512, 512);
    ln_kernel<<<dim3(4096), 256, 0, stream>>>(tb, bufC, tf_ln1g + l * 512,
                                              tf_ln1b + l * 512, tb, tbh);
    gemm_bf16_kernel<1><<<dim3(128 * 16), 256, 0, stream>>>(
        tbh, w1t_b + (size_t)l * 1048576, tf_b1 + l * 2048, qkvh,
        16384, 2048, 512);
    gemm_bf16_kernel<0><<<dim3(128 * 4), 256, 0, stream>>>(
        qkvh, w2t_b + (size_t)l * 1048576, tf_b2 + l * 512, bufC,
        16384, 512, 2048);
    ln_kernel<<<dim3(4096), 256, 0, stream>>>(tb, bufC, tf_ln2g + l * 512,
                                              tf_ln2b + l * 512, tb, tbh);
  }
  ln_kernel<<<dim3(4096), 256, 0, stream>>>(tb, nullptr, fin_g, fin_b, yout,
                                            nullptr);

  (void)in_sizes; (void)n_in; (void)out_size; (void)ws_size;
}

// Round 8
// 1813.515 us; speedup vs baseline: 1.0782x; 1.0687x over previous
//
#include <hip/hip_runtime.h>

// PatchVQVAETransformer forward, round 8:
//  - VQ scores S = z @ cb^T moved to MFMA via bf16x3 split-precision
//    (S = zh*ch + zh*cl + zl*ch, f32 accum; error ~1e-7 rms, same order as
//    the f32-reorder error already tolerated). f32 VALU GEMM removed.
//  - zh/zl split fused into pkB's z write; ch/cl split fused into cbnorm.
//  - everything else unchanged from r7.

#define SQRT1_2F 0.70710678118654752440f

typedef __attribute__((ext_vector_type(8))) short short8;
typedef __attribute__((ext_vector_type(4))) float f32x4;
typedef __attribute__((ext_vector_type(8))) unsigned short ushort8;
typedef unsigned short ushort;

__device__ __forceinline__ float gelu_exact(float v) {
  return 0.5f * v * (1.0f + erff(v * SQRT1_2F));
}

__device__ __forceinline__ ushort f2b_rne(float f) {
  unsigned u = __float_as_uint(f);
  unsigned r = (u + 0x7fffu + ((u >> 16) & 1u)) >> 16;
  return (ushort)r;
}

__device__ __forceinline__ float b2f(ushort u) {
  return __uint_as_float(((unsigned)u) << 16);
}

__device__ __forceinline__ void gload16(const void* g, void* l) {
  __builtin_amdgcn_global_load_lds(
      (const __attribute__((address_space(1))) void*)g,
      (__attribute__((address_space(3))) void*)l, 16, 0, 0);
}

// ---------------------------------------------------------------------------
// One-time setup: q16 = lq@wq^T + bq, wkvT, woutT. 1 block, 64 threads.
// ---------------------------------------------------------------------------
__global__ __launch_bounds__(64) void patch_setup_kernel(
    const float* __restrict__ lq, const float* __restrict__ win,
    const float* __restrict__ bin, const float* __restrict__ wout,
    float* __restrict__ q16, float* __restrict__ wkvT,
    float* __restrict__ woutT) {
  const int tid = threadIdx.x;
#pragma unroll
  for (int q = 0; q < 8; q++) {
    int e = tid + (q << 6);
    int i = e >> 5, c = e & 31;
    const float* wr = win + (size_t)c * 32;
    float acc = bin[c];
#pragma unroll
    for (int d = 0; d < 32; d++) acc += lq[(i << 5) + d] * wr[d];
    q16[e] = acc;
  }
#pragma unroll
  for (int q = 0; q < 32; q++) {
    int e = tid + (q << 6);
    int w = e >> 10, d = (e >> 5) & 31, c = e & 31;
    wkvT[e] = win[(size_t)(32 + (w << 5) + c) * 32 + d];
  }
#pragma unroll
  for (int q = 0; q < 16; q++) {
    int e = tid + (q << 6);
    int d = e >> 5, c = e & 31;
    woutT[e] = wout[(size_t)c * 32 + d];
  }
}

// ---------------------------------------------------------------------------
// LN over 16 rows x 32 cols at row-stride 34 in LDS, in place. 4 lanes/row.
// ---------------------------------------------------------------------------
__device__ __forceinline__ void ln_16xS(float* buf, const float* g,
                                        const float* bb, int tid) {
  int row = tid >> 2, sub = tid & 3;
  int c0 = sub << 3;
  float* r = buf + row * 34 + c0;
  float v[8];
  float s = 0.f, s2 = 0.f;
#pragma unroll
  for (int n = 0; n < 8; n++) {
    float t = r[n];
    v[n] = t; s += t; s2 += t * t;
  }
  s += __shfl_xor(s, 1);  s += __shfl_xor(s, 2);
  s2 += __shfl_xor(s2, 1); s2 += __shfl_xor(s2, 2);
  float m = s * (1.0f / 32.0f);
  float var = s2 * (1.0f / 32.0f) - m * m;
  float inv = 1.0f / sqrtf(var + 1e-5f);
#pragma unroll
  for (int n = 0; n < 8; n++)
    r[n] = (v[n] - m) * inv * g[c0 + n] + bb[c0 + n];
}

// ---------------------------------------------------------------------------
// pkA: in-proj + scores/softmax/AV for 4 patches per 256-thr block.
// Bit-exact vs r7. Writes so (16384x512) -> bufA.
// ---------------------------------------------------------------------------
__global__ __launch_bounds__(256) void pkA_kernel(
    const float* __restrict__ x, const float* __restrict__ pos,
    const float* __restrict__ wkvT, const float* __restrict__ bin,
    const float* __restrict__ q16, float* __restrict__ so) {
  __shared__ float sxp[2048];
  __shared__ float skv[4096];
  __shared__ float sq16[16 * 33];
  const int blk = blockIdx.x, t = threadIdx.x;
  const int p0 = blk << 2;

#pragma unroll
  for (int q = 0; q < 8; q++) {
    int e = t + (q << 8);
    int pl = e >> 9, r = e & 511;
    sxp[e] = x[(size_t)(p0 + pl) * 512 + r] + pos[r];
  }
  if (t < 128) {
#pragma unroll
    for (int q = 0; q < 4; q++) {
      int e = t + (q << 7);
      sq16[(e >> 5) * 33 + (e & 31)] = q16[e];
    }
  }
  __syncthreads();

#pragma unroll
  for (int q = 0; q < 16; q++) {
    int e = t + (q << 8);
    int pl = e >> 10, rr = e & 1023;
    int w = rr >> 9, rj = rr & 511, j = rj >> 5, c = rj & 31;
    const float* wt = wkvT + (w << 10) + c;
    const float* sx = sxp + (pl << 9) + (j << 5);
    float acc = bin[32 + (w << 5) + c];
#pragma unroll
    for (int d = 0; d < 32; d++) acc += sx[d] * wt[d << 5];
    skv[e] = acc;
  }
  __syncthreads();

  const int pl = t >> 6, hh = (t >> 4) & 3, i = t & 15;
  const int p = p0 + pl;
  const float* kp = skv + (pl << 10);
  const int hd = hh << 3;

  float sc[16];
#pragma unroll
  for (int j = 0; j < 16; j++) {
    float acc = 0.f;
#pragma unroll
    for (int d = 0; d < 8; d++)
      acc += sq16[i * 33 + hd + d] * kp[(j << 5) + hd + d];
    sc[j] = acc * 0.35355339059327373f;
  }
  {
    float mx = sc[0];
#pragma unroll
    for (int j = 1; j < 16; j++) mx = fmaxf(mx, sc[j]);
    float sm = 0.f;
    float ev[16];
#pragma unroll
    for (int j = 0; j < 16; j++) { ev[j] = expf(sc[j] - mx); sm += ev[j]; }
    float inv = 1.0f / sm;
#pragma unroll
    for (int j = 0; j < 16; j++) sc[j] = ev[j] * inv;
  }
  float* orow = so + (size_t)p * 512 + (i << 5) + hd;
#pragma unroll
  for (int c8 = 0; c8 < 8; c8++) {
    const int c = hd + c8;
    float acc = 0.f;
#pragma unroll
    for (int j = 0; j < 16; j++) acc += sc[j] * kp[512 + (j << 5) + c];
    orow[c8] = acc;
  }
}

// ---------------------------------------------------------------------------
// pkB: out-proj+LN1+FFN1+FFN2+LN2+z per patch (64 thr). Bit-exact z; also
// emits the exact two-term bf16 split zh/zl for the MFMA VQ GEMM.
// ---------------------------------------------------------------------------
__global__ __launch_bounds__(64) void pkB_kernel(
    const float* __restrict__ so_g, const float* __restrict__ x,
    const float* __restrict__ woutT, const float* __restrict__ bout,
    const float* __restrict__ lq,
    const float* __restrict__ ln1g, const float* __restrict__ ln1b,
    const float* __restrict__ w1, const float* __restrict__ b1,
    const float* __restrict__ w2, const float* __restrict__ b2,
    const float* __restrict__ ln2g, const float* __restrict__ ln2b,
    float* __restrict__ z, ushort* __restrict__ zh,
    ushort* __restrict__ zl) {
  __shared__ float sso[544], sst[544], ssh[1056];
  const int p = blockIdx.x, t = threadIdx.x;
#pragma unroll
  for (int q = 0; q < 8; q++) {
    int e = t + (q << 6);
    sso[(e >> 5) * 34 + (e & 31)] = so_g[(size_t)p * 512 + e];
  }
  __syncthreads();
#pragma unroll
  for (int q = 0; q < 8; q++) {
    int e = t + (q << 6);
    int i = e >> 5, c = e & 31;
    const float* wt = woutT + c;
    float acc = bout[c];
#pragma unroll
    for (int d = 0; d < 32; d++) acc += sso[i * 34 + d] * wt[d << 5];
    sst[i * 34 + c] = acc + lq[(i << 5) + c];
  }
  __syncthreads();
  ln_16xS(sst, ln1g, ln1b, t);
  __syncthreads();
#pragma unroll
  for (int q = 0; q < 16; q++) {
    int i = q, u = t;
    float acc = b1[u];
#pragma unroll
    for (int d = 0; d < 32; d++) acc += sst[i * 34 + d] * w1[(d << 6) + u];
    ssh[i * 66 + u] = gelu_exact(acc);
  }
  __syncthreads();
#pragma unroll
  for (int q = 0; q < 8; q++) {
    int e = t + (q << 6);
    int i = e >> 5, c = e & 31;
    float acc = b2[c];
#pragma unroll
    for (int u = 0; u < 64; u++) acc += ssh[i * 66 + u] * w2[(u << 5) + c];
    sso[i * 34 + c] = acc + sst[i * 34 + c];
  }
  __syncthreads();
  ln_16xS(sso, ln2g, ln2b, t);
  __syncthreads();
  const float* xp = x + (size_t)p * 512;
#pragma unroll
  for (int q = 0; q < 8; q++) {
    int e = t + (q << 6);
    float zv = xp[e] + sso[(e >> 5) * 34 + (e & 31)];
    z[(size_t)p * 512 + e] = zv;
    ushort h = f2b_rne(zv);
    zh[(size_t)p * 512 + e] = h;
    zl[(size_t)p * 512 + e] = f2b_rne(zv - b2f(h));
  }
}

// ---------------------------------------------------------------------------
// cbnorm + bf16 split of the codebook (ch/cl).
// ---------------------------------------------------------------------------
__global__ __launch_bounds__(64) void cbnorm_kernel(
    const float* __restrict__ cb, float* __restrict__ cbn,
    ushort* __restrict__ ch, ushort* __restrict__ cl) {
  int c = blockIdx.x, lane = threadIdx.x;
  const float* r = cb + (size_t)c * 512 + lane * 8;
  float v[8];
  *(float4*)(v)     = *(const float4*)(r);
  *(float4*)(v + 4) = *(const float4*)(r + 4);
  float s = 0.f;
  ushort8 hv, lv;
#pragma unroll
  for (int n = 0; n < 8; n++) {
    s += v[n] * v[n];
    ushort h = f2b_rne(v[n]);
    hv[n] = h;
    lv[n] = f2b_rne(v[n] - b2f(h));
  }
  *(ushort8*)(ch + (size_t)c * 512 + lane * 8) = hv;
  *(ushort8*)(cl + (size_t)c * 512 + lane * 8) = lv;
#pragma unroll
  for (int off = 1; off < 64; off <<= 1) s += __shfl_xor(s, off);
  if (lane == 0) cbn[c] = s;
}

// ---------------------------------------------------------------------------
// VQ scores via bf16x3 MFMA: S = zh@ch^T + zh@cl^T + zl@ch^T (f32 accum).
// M=16384, N=1024, K=512. 128x128 tile, BK=32, 4 waves, 4x4 frags.
// ---------------------------------------------------------------------------
__global__ __launch_bounds__(256) void gemm_vq_b3(
    const ushort* __restrict__ Ah, const ushort* __restrict__ Al,
    const ushort* __restrict__ Bh, const ushort* __restrict__ Bl,
    float* __restrict__ C) {
  __shared__ ushort sAh[4096], sAl[4096], sBh[4096], sBl[4096];
  const int bx = blockIdx.x & 7, by = blockIdx.x >> 3;
  const int m0 = by << 7, n0 = bx << 7;
  const int tid = threadIdx.x;
  const int wid = tid >> 6, lane = tid & 63;
  const int wr = wid >> 1, wc = wid & 1;
  const int l15 = lane & 15, lk = lane >> 4;

  const f32x4 fzero = {0.f, 0.f, 0.f, 0.f};
  f32x4 acc[4][4];
#pragma unroll
  for (int i = 0; i < 4; i++)
#pragma unroll
    for (int j = 0; j < 4; j++) acc[i][j] = fzero;

  for (int k0 = 0; k0 < 512; k0 += 32) {
#pragma unroll
    for (int c = 0; c < 2; c++) {
      const int I = tid + (c << 8);
      const int r = I >> 2, kk = (I & 3) << 3;
      const size_t ga = (size_t)(m0 + r) * 512 + k0 + kk;
      const size_t gb = (size_t)(n0 + r) * 512 + k0 + kk;
      const size_t lo = (size_t)((wid << 6) + (c << 8)) * 8;
      gload16(Ah + ga, sAh + lo);
      gload16(Al + ga, sAl + lo);
      gload16(Bh + gb, sBh + lo);
      gload16(Bl + gb, sBl + lo);
    }
    __syncthreads();

    short8 ah[4], al[4], bh[4], bl[4];
#pragma unroll
    for (int m = 0; m < 4; m++) {
      const int ar = ((wr << 6) + (m << 4) + l15) * 32 + lk * 8;
      ah[m] = *(const short8*)(sAh + ar);
      al[m] = *(const short8*)(sAl + ar);
      const int br = ((wc << 6) + (m << 4) + l15) * 32 + lk * 8;
      bh[m] = *(const short8*)(sBh + br);
      bl[m] = *(const short8*)(sBl + br);
    }
#pragma unroll
    for (int m = 0; m < 4; m++)
#pragma unroll
      for (int n = 0; n < 4; n++) {
        acc[m][n] = __builtin_amdgcn_mfma_f32_16x16x32_bf16(ah[m], bh[n],
                                                            acc[m][n], 0, 0, 0);
        acc[m][n] = __builtin_amdgcn_mfma_f32_16x16x32_bf16(ah[m], bl[n],
                                                            acc[m][n], 0, 0, 0);
        acc[m][n] = __builtin_amdgcn_mfma_f32_16x16x32_bf16(al[m], bh[n],
                                                            acc[m][n], 0, 0, 0);
      }
    __syncthreads();
  }

#pragma unroll
  for (int m = 0; m < 4; m++)
#pragma unroll
    for (int n = 0; n < 4; n++) {
      const int gcol = n0 + (wc << 6) + (n << 4) + l15;
#pragma unroll
      for (int r = 0; r < 4; r++) {
        const int grow = m0 + (wr << 6) + (m << 4) + (lk << 2) + r;
        C[(size_t)grow * 1024 + gcol] = acc[m][n][r];
      }
    }
}

// ---------------------------------------------------------------------------
// bf16 MFMA GEMM (unchanged from r3-r7).
// ---------------------------------------------------------------------------
template <int OUTMODE>
__global__ __launch_bounds__(256) void gemm_bf16_kernel(
    const ushort* __restrict__ A, const ushort* __restrict__ B,
    const float* __restrict__ bias, void* __restrict__ Cout,
    int M, int N, int K) {
  __shared__ ushort As[4096];
  __shared__ ushort Bs[4096];
  const int nbx = N >> 7;
  const int bx = blockIdx.x % nbx, by = blockIdx.x / nbx;
  const int m0 = by << 7, n0 = bx << 7;
  const int tid = threadIdx.x;
  const int wid = tid >> 6, lane = tid & 63;
  const int wr = wid >> 1, wc = wid & 1;
  const int l15 = lane & 15, lk = lane >> 4;

  const f32x4 fzero = {0.f, 0.f, 0.f, 0.f};
  f32x4 acc[4][4];
#pragma unroll
  for (int i = 0; i < 4; i++)
#pragma unroll
    for (int j = 0; j < 4; j++) acc[i][j] = fzero;

  for (int k0 = 0; k0 < K; k0 += 32) {
#pragma unroll
    for (int c = 0; c < 2; c++) {
      const int I = tid + (c << 8);
      const int r = I >> 2, kk = (I & 3) << 3;
      gload16(A + (size_t)(m0 + r) * K + k0 + kk,
              As + (size_t)((wid << 6) + (c << 8)) * 8);
      gload16(B + (size_t)(n0 + r) * K + k0 + kk,
              Bs + (size_t)((wid << 6) + (c << 8)) * 8);
    }
    __syncthreads();

    short8 a[4], b[4];
#pragma unroll
    for (int m = 0; m < 4; m++) {
      const int ar = (wr << 6) + (m << 4) + l15;
      a[m] = *(const short8*)(As + ar * 32 + lk * 8);
      const int br = (wc << 6) + (m << 4) + l15;
      b[m] = *(const short8*)(Bs + br * 32 + lk * 8);
    }
#pragma unroll
    for (int m = 0; m < 4; m++)
#pragma unroll
      for (int n = 0; n < 4; n++)
        acc[m][n] = __builtin_amdgcn_mfma_f32_16x16x32_bf16(a[m], b[n],
                                                            acc[m][n], 0, 0, 0);
    __syncthreads();
  }

  float bv[4];
#pragma unroll
  for (int n = 0; n < 4; n++)
    bv[n] = bias[n0 + (wc << 6) + (n << 4) + l15];

#pragma unroll
  for (int m = 0; m < 4; m++) {
#pragma unroll
    for (int n = 0; n < 4; n++) {
      const int gcol = n0 + (wc << 6) + (n << 4) + l15;
#pragma unroll
      for (int r = 0; r < 4; r++) {
        const int grow = m0 + (wr << 6) + (m << 4) + (lk << 2) + r;
        float v = acc[m][n][r] + bv[n];
        if (OUTMODE == 0) {
          ((float*)Cout)[(size_t)grow * N + gcol] = v;
        } else if (OUTMODE == 1) {
          ((ushort*)Cout)[(size_t)grow * N + gcol] = f2b_rne(gelu_exact(v));
        } else {
          ((ushort*)Cout)[(size_t)grow * N + gcol] = f2b_rne(v);
        }
      }
    }
  }
}

// ---------------------------------------------------------------------------
// Weight conversions.
// ---------------------------------------------------------------------------
__global__ void cvt_flat(const float* __restrict__ in, ushort* __restrict__ out,
                         int n) {
  int i = blockIdx.x * blockDim.x + threadIdx.x;
  const int stride = gridDim.x * blockDim.x;
  for (; i < n; i += stride) out[i] = f2b_rne(in[i]);
}

__global__ __launch_bounds__(256) void cvt_tr(const float* __restrict__ in,
                                              ushort* __restrict__ out,
                                              int R, int C) {
  __shared__ float tile[32][33];
  const int bc = blockIdx.x, br = blockIdx.y, lay = blockIdx.z;
  const float* src = in + (size_t)lay * R * C;
  ushort* dst = out + (size_t)lay * R * C;
  const int tid = threadIdx.x;
#pragma unroll
  for (int q = 0; q < 4; q++) {
    int idx = tid + (q << 8);
    int rr = idx >> 5, cc = idx & 31;
    tile[rr][cc] = src[(size_t)(br * 32 + rr) * C + bc * 32 + cc];
  }
  __syncthreads();
#pragma unroll
  for (int q = 0; q < 4; q++) {
    int idx = tid + (q << 8);
    int co = idx >> 5, ro = idx & 31;
    dst[(size_t)(bc * 32 + co) * R + br * 32 + ro] = f2b_rne(tile[ro][co]);
  }
}

// ---------------------------------------------------------------------------
// VQ finish (f32 exact argmin over d = znorm + cbnorm - 2S).
// ---------------------------------------------------------------------------
__global__ __launch_bounds__(64) void vq_finish_kernel(
    const float* __restrict__ S, const float* __restrict__ cb,
    const float* __restrict__ cbn, const float* __restrict__ z,
    const float* __restrict__ tf_pos, float* __restrict__ t,
    ushort* __restrict__ th,
    float* __restrict__ idx_out, float* __restrict__ loss_out) {
  const int r = blockIdx.x, lane = threadIdx.x;
  const float* zr = z + (size_t)r * 512;

  float s2 = 0.f;
  {
    const float* zp = zr + lane * 8;
    float4 a = *(const float4*)zp, b = *(const float4*)(zp + 4);
    s2 = a.x*a.x + a.y*a.y + a.z*a.z + a.w*a.w +
         b.x*b.x + b.y*b.y + b.z*b.z + b.w*b.w;
  }
#pragma unroll
  for (int off = 1; off < 64; off <<= 1) s2 += __shfl_xor(s2, off);

  const float* Sr = S + (size_t)r * 1024;
  float best = __int_as_float(0x7f7fffff);
  int bi = 0x7fffffff;
  for (int c = lane; c < 1024; c += 64) {
    float d = (s2 + cbn[c]) - 2.0f * Sr[c];
    if (d < best) { best = d; bi = c; }
  }
#pragma unroll
  for (int off = 1; off < 64; off <<= 1) {
    float ob = __shfl_xor(best, off);
    int oi = __shfl_xor(bi, off);
    if (ob < best || (ob == best && oi < bi)) { best = ob; bi = oi; }
  }

  const float* q = cb + (size_t)bi * 512;
  const float* pr = tf_pos + (size_t)(r & 255) * 512;
  float lsum = 0.f;
  float tv[8];
#pragma unroll
  for (int n = 0; n < 8; n++) {
    int c = lane * 8 + n;
    float qv = q[c];
    float diff = qv - zr[c];
    lsum += diff * diff;
    tv[n] = qv + pr[c];
    t[(size_t)r * 512 + c] = tv[n];
  }
  {
    ushort8 w;
#pragma unroll
    for (int n = 0; n < 8; n++) w[n] = f2b_rne(tv[n]);
    *(ushort8*)(th + (size_t)r * 512 + lane * 8) = w;
  }
#pragma unroll
  for (int off = 1; off < 64; off <<= 1) lsum += __shfl_xor(lsum, off);
  if (lane == 0) {
    atomicAdd(loss_out, lsum * (1.25f / 8388608.0f));
    idx_out[r] = (float)bi;
  }
}

// ---------------------------------------------------------------------------
// MFMA flash attention (unchanged from r5-r7).
// ---------------------------------------------------------------------------
__global__ __launch_bounds__(64) void attn_mfma_kernel(
    const ushort* __restrict__ qkv, ushort* __restrict__ o) {
  __shared__ ushort lds[8192];
  char* KsB = (char*)lds;
  char* VtB = (char*)(lds + 4096);
  const int bid = blockIdx.x;
  const int xcd = bid & 7, slot = bid >> 3;
  const int b = (xcd << 3) | (slot >> 5);
  const int h = (slot >> 2) & 7;
  const int qb = slot & 3;
  const int lane = threadIdx.x;
  const int l15 = lane & 15, lk4 = lane >> 4;

  short8 qf[4][2];
#pragma unroll
  for (int m = 0; m < 4; m++)
#pragma unroll
    for (int kc = 0; kc < 2; kc++)
      qf[m][kc] = *(const short8*)(qkv +
          (size_t)(b * 256 + qb * 64 + m * 16 + l15) * 1536 +
          h * 64 + kc * 32 + lk4 * 8);

  const f32x4 fz = {0.f, 0.f, 0.f, 0.f};
  f32x4 O[4][4];
#pragma unroll
  for (int m = 0; m < 4; m++)
#pragma unroll
    for (int n = 0; n < 4; n++) O[m][n] = fz;
  float lsum[4][4];
#pragma unroll
  for (int m = 0; m < 4; m++)
#pragma unroll
    for (int r = 0; r < 4; r++) lsum[m][r] = 0.f;

  for (int jt = 0; jt <= qb; jt++) {
    ushort8 kv[8], vv[8];
    const ushort* krow = qkv + (size_t)(b * 256 + jt * 64 + lane) * 1536 +
                         512 + h * 64;
#pragma unroll
    for (int u = 0; u < 8; u++) kv[u] = ((const ushort8*)krow)[u];
#pragma unroll
    for (int u = 0; u < 8; u++) vv[u] = ((const ushort8*)(krow + 512))[u];
    __syncthreads();
    {
      const int rx = (lane & 7) << 4;
#pragma unroll
      for (int u = 0; u < 8; u++)
        *(ushort8*)(KsB + lane * 128 + ((u << 4) ^ rx)) = kv[u];
#pragma unroll
      for (int u = 0; u < 8; u++)
#pragma unroll
        for (int i = 0; i < 8; i++) {
          const int d = u * 8 + i;
          *(ushort*)(VtB + ((d * 128 + lane * 2) ^ ((d & 7) << 4))) =
              (ushort)vv[u][i];
        }
    }
    __syncthreads();

    f32x4 sacc[4][4];
#pragma unroll
    for (int m = 0; m < 4; m++)
#pragma unroll
      for (int n = 0; n < 4; n++) sacc[m][n] = fz;
#pragma unroll
    for (int kc = 0; kc < 2; kc++) {
      short8 bf[4];
#pragma unroll
      for (int n = 0; n < 4; n++) {
        const int row = n * 16 + l15;
        bf[n] = *(const short8*)(KsB + row * 128 +
                                 ((kc * 64 + lk4 * 16) ^ ((row & 7) << 4)));
      }
#pragma unroll
      for (int m = 0; m < 4; m++)
#pragma unroll
        for (int n = 0; n < 4; n++)
          sacc[m][n] = __builtin_amdgcn_mfma_f32_16x16x32_bf16(
              qf[m][kc], bf[n], sacc[m][n], 0, 0, 0);
    }
    __syncthreads();

    const bool diag = (jt == qb);
#pragma unroll
    for (int m = 0; m < 4; m++)
#pragma unroll
      for (int n = 0; n < 4; n++)
#pragma unroll
        for (int r = 0; r < 4; r++) {
          const int ql = m * 16 + lk4 * 4 + r;
          const int jl = n * 16 + l15;
          float e = __expf(sacc[m][n][r] * 0.125f);
          if (diag && jl > ql) e = 0.f;
          const ushort pu = f2b_rne(e);
          lsum[m][r] += b2f(pu);
          *(ushort*)(KsB + ql * 128 + ((jl * 2) ^ ((ql & 7) << 4))) = pu;
        }
    __syncthreads();

#pragma unroll
    for (int kc = 0; kc < 2; kc++) {
      short8 pf[4], vf[4];
#pragma unroll
      for (int m = 0; m < 4; m++) {
        const int row = m * 16 + l15;
        pf[m] = *(const short8*)(KsB + row * 128 +
                                 ((kc * 64 + lk4 * 16) ^ ((row & 7) << 4)));
      }
#pragma unroll
      for (int n = 0; n < 4; n++) {
        const int row = n * 16 + l15;
        vf[n] = *(const short8*)(VtB + row * 128 +
                                 ((kc * 64 + lk4 * 16) ^ ((row & 7) << 4)));
      }
#pragma unroll
      for (int m = 0; m < 4; m++)
#pragma unroll
        for (int n = 0; n < 4; n++)
          O[m][n] = __builtin_amdgcn_mfma_f32_16x16x32_bf16(
              pf[m], vf[n], O[m][n], 0, 0, 0);
    }
  }

  float inv[4][4];
#pragma unroll
  for (int m = 0; m < 4; m++)
#pragma unroll
    for (int r = 0; r < 4; r++) {
      float v = lsum[m][r];
      v += __shfl_xor(v, 1); v += __shfl_xor(v, 2);
      v += __shfl_xor(v, 4); v += __shfl_xor(v, 8);
      inv[m][r] = 1.0f / v;
    }
#pragma unroll
  for (int m = 0; m < 4; m++)
#pragma unroll
    for (int n = 0; n < 4; n++)
#pragma unroll
      for (int r = 0; r < 4; r++) {
        const int row = b * 256 + qb * 64 + m * 16 + lk4 * 4 + r;
        const int col = h * 64 + n * 16 + l15;
        o[(size_t)row * 512 + col] = f2b_rne(O[m][n][r] * inv[m][r]);
      }
}

// ---------------------------------------------------------------------------
// LayerNorm over 512 (+residual). Writes f32 out and optional bf16 copy.
// ---------------------------------------------------------------------------
__global__ __launch_bounds__(256) void ln_kernel(
    const float* __restrict__ xin, const float* __restrict__ addin,
    const float* __restrict__ g, const float* __restrict__ bb,
    float* __restrict__ outp, ushort* __restrict__ outb) {
  const int r = blockIdx.x * 4 + (threadIdx.x >> 6);
  const int lane = threadIdx.x & 63;
  const float* xr = xin + (size_t)r * 512 + lane * 8;
  float v[8];
  *(float4*)(v)     = *(const float4*)(xr);
  *(float4*)(v + 4) = *(const float4*)(xr + 4);
  if (addin) {
    const float* ar = addin + (size_t)r * 512 + lane * 8;
    float w[8];
    *(float4*)(w)     = *(const float4*)(ar);
    *(float4*)(w + 4) = *(const float4*)(ar + 4);
#pragma unroll
    for (int n = 0; n < 8; n++) v[n] += w[n];
  }
  float s = 0.f, s2 = 0.f;
#pragma unroll
  for (int n = 0; n < 8; n++) { s += v[n]; s2 += v[n] * v[n]; }
#pragma unroll
  for (int off = 1; off < 64; off <<= 1) {
    s += __shfl_xor(s, off);
    s2 += __shfl_xor(s2, off);
  }
  float m = s * (1.0f / 512.0f);
  float var = s2 * (1.0f / 512.0f) - m * m;
  float inv = 1.0f / sqrtf(var + 1e-5f);
  const int c0 = lane * 8;
  float outv[8];
#pragma unroll
  for (int n = 0; n < 8; n++) outv[n] = (v[n] - m) * inv * g[c0 + n] + bb[c0 + n];
  float* orow = outp + (size_t)r * 512 + c0;
  *(float4*)(orow)     = *(float4*)(outv);
  *(float4*)(orow + 4) = *(float4*)(outv + 4);
  if (outb) {
    ushort8 w;
#pragma unroll
    for (int n = 0; n < 8; n++) w[n] = f2b_rne(outv[n]);
    *(ushort8*)(outb + (size_t)r * 512 + c0) = w;
  }
}

// ---------------------------------------------------------------------------
extern "C" void kernel_launch(void* const* d_in, const int* in_sizes, int n_in,
                              void* d_out, int out_size, void* d_ws, size_t ws_size,
                              hipStream_t stream) {
  const float* x       = (const float*)d_in[0];
  const float* pa_lq   = (const float*)d_in[1];
  const float* pa_pos  = (const float*)d_in[2];
  const float* pa_win  = (const float*)d_in[3];
  const float* pa_bin  = (const float*)d_in[4];
  const float* pa_wout = (const float*)d_in[5];
  const float* pa_bout = (const float*)d_in[6];
  const float* pa_ln1g = (const float*)d_in[7];
  const float* pa_ln1b = (const float*)d_in[8];
  const float* pa_ln2g = (const float*)d_in[9];
  const float* pa_ln2b = (const float*)d_in[10];
  const float* pa_w1   = (const float*)d_in[11];
  const float* pa_b1   = (const float*)d_in[12];
  const float* pa_w2   = (const float*)d_in[13];
  const float* pa_b2   = (const float*)d_in[14];
  const float* cb      = (const float*)d_in[15];
  const float* tf_pos  = (const float*)d_in[16];
  const float* tf_win  = (const float*)d_in[17];
  const float* tf_bin  = (const float*)d_in[18];
  const float* tf_wout = (const float*)d_in[19];
  const float* tf_bout = (const float*)d_in[20];
  const float* tf_ln1g = (const float*)d_in[21];
  const float* tf_ln1b = (const float*)d_in[22];
  const float* tf_ln2g = (const float*)d_in[23];
  const float* tf_ln2b = (const float*)d_in[24];
  const float* tf_w1   = (const float*)d_in[25];
  const float* tf_b1   = (const float*)d_in[26];
  const float* tf_w2   = (const float*)d_in[27];
  const float* tf_b2   = (const float*)d_in[28];
  const float* fin_g   = (const float*)d_in[29];
  const float* fin_b   = (const float*)d_in[30];

  float* yout = (float*)d_out;            // 16384 x 512
  float* loss_out = yout + 8388608;       // scalar
  float* idx_out = loss_out + 1;          // 16384 (as float)

  float* ws   = (float*)d_ws;
  float* z    = ws;                   // 8388608
  float* tb   = z + 8388608;          // 8388608
  float* bufA = tb + 8388608;         // 16777216 (patch: so ; VQ: S ; tf: qkv)
  float* bufC = bufA + 16777216;      // 8388608  (patch: zh/zl ; tf: proj out)
  float* wreg = bufC + 8388608;       // 6291456
  float* treg = wreg + 6291456;       // 4194304  (VQ: ch/cl ; tf: tbh)
  float* cbn  = treg + 4194304;       // 1024
  float* q16  = cbn + 1024;           // 512
  float* wkvT = q16 + 512;            // 2048
  float* woutT = wkvT + 2048;         // 1024

  ushort* win_b  = (ushort*)wreg;
  ushort* wout_b = win_b + 3145728;
  ushort* w1t_b  = wout_b + 1048576;
  ushort* w2t_b  = w1t_b + 4194304;
  ushort* tbh    = (ushort*)treg;
  ushort* qkvh   = (ushort*)bufA;
  ushort* abh    = (ushort*)z;
  ushort* zh_b   = (ushort*)bufC;          // 8388608 ushorts
  ushort* zl_b   = zh_b + 8388608;         // 8388608 ushorts (fills bufC)
  ushort* ch_b   = (ushort*)treg;          // 524288 (dead before tbh written)
  ushort* cl_b   = ch_b + 524288;

  hipMemsetAsync(loss_out, 0, sizeof(float), stream);
  cbnorm_kernel<<<1024, 64, 0, stream>>>(cb, cbn, ch_b, cl_b);
  patch_setup_kernel<<<1, 64, 0, stream>>>(pa_lq, pa_win, pa_bin, pa_wout,
                                           q16, wkvT, woutT);

  // patch encoder (bit-exact vs r7); so -> bufA, z + bf16-split -> z/bufC
  pkA_kernel<<<4096, 256, 0, stream>>>(x, pa_pos, wkvT, pa_bin, q16, bufA);
  pkB_kernel<<<16384, 64, 0, stream>>>(bufA, x, woutT, pa_bout, pa_lq,
                                       pa_ln1g, pa_ln1b, pa_w1, pa_b1,
                                       pa_w2, pa_b2, pa_ln2g, pa_ln2b, z,
                                       zh_b, zl_b);

  cvt_flat<<<2048, 256, 0, stream>>>(tf_win, win_b, 3145728);
  cvt_flat<<<1024, 256, 0, stream>>>(tf_wout, wout_b, 1048576);
  cvt_tr<<<dim3(64, 16, 4), 256, 0, stream>>>(tf_w1, w1t_b, 512, 2048);
  cvt_tr<<<dim3(16, 64, 4), 256, 0, stream>>>(tf_w2, w2t_b, 2048, 512);

  // VQ scores on MFMA (bf16x3), then exact f32 finish
  gemm_vq_b3<<<dim3(1024), 256, 0, stream>>>(zh_b, zl_b, ch_b, cl_b, bufA);
  vq_finish_kernel<<<16384, 64, 0, stream>>>(bufA, cb, cbn, z, tf_pos, tb, tbh,
                                             idx_out, loss_out);

  for (int l = 0; l < 4; l++) {
    gemm_bf16_kernel<2><<<dim3(128 * 12), 256, 0, stream>>>(
        tbh, win_b + (size_t)l * 1536 * 512, tf_bin + l * 1536, qkvh,
        16384, 1536, 512);
    attn_mfma_kernel<<<dim3(2048), 64, 0, stream>>>(qkvh, abh);
    gemm_bf16_kernel<0><<<dim3(128 * 4), 256, 0, stream>>>(
        abh, wout_b + (size_t)l * 512 * 512, tf_bout + l * 512, bufC,
        16384, 512, 512);
    ln_kernel<<<dim3(4096), 256, 0, stream>>>(tb, bufC, tf_ln1g + l * 512,
                                              tf_ln1b + l * 512, tb, tbh);
    gemm_bf16_kernel<1><<<dim3(128 * 16), 256, 0, stream>>>(
        tbh, w1t_b + (size_t)l * 1048576, tf_b1 + l * 2048, qkvh,
        16384, 2048, 512);
    gemm_bf16_kernel<0><<<dim3(128 * 4), 256, 0, stream>>>(
        qkvh, w2t_b + (size_t)l * 1048576, tf_b2 + l * 512, bufC,
        16384, 512, 2048);
    ln_kernel<<<dim3(4096), 256, 0, stream>>>(tb, bufC, tf_ln2g + l * 512,
                                              tf_ln2b + l * 512, tb, tbh);
  }
  ln_kernel<<<dim3(4096), 256, 0, stream>>>(tb, nullptr, fin_g, fin_b, yout,
                                            nullptr);

  (void)in_sizes; (void)n_in; (void)out_size; (void)ws_size;
}